// Round 6
// baseline (2697.541 us; speedup 1.0000x reference)
//
#include <hip/hip_runtime.h>
#include <hip/hip_cooperative_groups.h>
#include <cmath>

namespace cg = cooperative_groups;

#define WIN 64
#define HID 512
#define BATCH 1024
#define KIN 518

typedef _Float16 f16;
typedef _Float16 half8 __attribute__((ext_vector_type(8)));
typedef float f32x4 __attribute__((ext_vector_type(4)));

struct Sched { int starts[63]; int ends[63]; };
struct SegMap { int idx[64]; };
struct GSteps { int g[32]; int n; };
struct TList { int t[64]; };
struct HTab { int v[64]; };

// ---------------------------------------------------------------------------
// Builder: dense per-position flag tables for the scan kernel.
// ---------------------------------------------------------------------------
__global__ __launch_bounds__(1024)
void build_flags(int* __restrict__ fe, int* __restrict__ sidx, Sched sc) {
  int tid = threadIdx.x;
  if (tid < 1000) fe[tid] = -1;
  __syncthreads();
  if (tid < 63) {
    fe[sc.ends[tid]] = tid;
    sidx[tid] = sc.starts[tid] / 50;
  }
}

// ---------------------------------------------------------------------------
// Parallel logsig scan (validated round 3). Writes lsh[t][b][64] fp16.
// ---------------------------------------------------------------------------
__global__ __launch_bounds__(256)
void logsig_scan(const float* __restrict__ z, const int* __restrict__ fe,
                 const int* __restrict__ sidx, ushort* __restrict__ lsh,
                 float scale) {
  __shared__ float zs[3000];
  __shared__ float Cs[20][3];
  __shared__ float wtot[4][6];
  __shared__ float earr[63][6];
  const int tid = threadIdx.x;
  const int b = blockIdx.x;
  const int ln = tid & 63, wv = tid >> 6;

  const float4* zrow = (const float4*)(z + (size_t)b * 3000);
  for (int i = tid; i < 750; i += 256) ((float4*)zs)[i] = zrow[i];
  if (tid == 0) { Cs[0][0] = 0.f; Cs[0][1] = 0.f; Cs[0][2] = 0.f; }

  const int p0 = 4 * tid + 1;
  int myfe[4];
#pragma unroll
  for (int i = 0; i < 4; ++i) myfe[i] = (p0 + i <= 999) ? fe[p0 + i] : -1;
  __syncthreads();

  float d0 = 0.f, d1 = 0.f, d2 = 0.f, A0 = 0.f, A1 = 0.f, A2 = 0.f;
  if (p0 <= 999) {
    float b0 = 0.f, b1 = 0.f, b2 = 0.f;
#pragma unroll
    for (int i = 0; i < 4; ++i) {
      int p = p0 + i;
      if (p > 999) break;
      float n0 = b0 + zs[p * 3 + 0] * scale;
      float n1 = b1 + zs[p * 3 + 1] * scale;
      float n2 = b2 + zs[p * 3 + 2] * scale;
      A0 += 0.5f * (b0 * n1 - b1 * n0);
      A1 += 0.5f * (b0 * n2 - b2 * n0);
      A2 += 0.5f * (b1 * n2 - b2 * n1);
      b0 = n0; b1 = n1; b2 = n2;
    }
    d0 = b0; d1 = b1; d2 = b2;
  }

#pragma unroll
  for (int off = 1; off < 64; off <<= 1) {
    float e0 = __shfl(d0, ln - off), e1 = __shfl(d1, ln - off), e2 = __shfl(d2, ln - off);
    float eA0 = __shfl(A0, ln - off), eA1 = __shfl(A1, ln - off), eA2 = __shfl(A2, ln - off);
    if (ln >= off) {
      A0 = eA0 + A0 + 0.5f * (e0 * d1 - e1 * d0);
      A1 = eA1 + A1 + 0.5f * (e0 * d2 - e2 * d0);
      A2 = eA2 + A2 + 0.5f * (e1 * d2 - e2 * d1);
      d0 += e0; d1 += e1; d2 += e2;
    }
  }
  if (ln == 63) {
    wtot[wv][0] = d0; wtot[wv][1] = d1; wtot[wv][2] = d2;
    wtot[wv][3] = A0; wtot[wv][4] = A1; wtot[wv][5] = A2;
  }
  __syncthreads();

  float P0 = 0.f, P1 = 0.f, P2 = 0.f, PA0 = 0.f, PA1 = 0.f, PA2 = 0.f;
  for (int w = 0; w < wv; ++w) {
    float t0 = wtot[w][0], t1 = wtot[w][1], t2 = wtot[w][2];
    PA0 = PA0 + wtot[w][3] + 0.5f * (P0 * t1 - P1 * t0);
    PA1 = PA1 + wtot[w][4] + 0.5f * (P0 * t2 - P2 * t0);
    PA2 = PA2 + wtot[w][5] + 0.5f * (P1 * t2 - P2 * t1);
    P0 += t0; P1 += t1; P2 += t2;
  }
  float L0 = __shfl(d0, ln - 1), L1 = __shfl(d1, ln - 1), L2 = __shfl(d2, ln - 1);
  float LA0 = __shfl(A0, ln - 1), LA1 = __shfl(A1, ln - 1), LA2 = __shfl(A2, ln - 1);
  if (ln == 0) { L0 = L1 = L2 = LA0 = LA1 = LA2 = 0.f; }
  float bp0 = P0 + L0, bp1 = P1 + L1, bp2 = P2 + L2;
  float C0 = PA0 + LA0 + 0.5f * (P0 * L1 - P1 * L0);
  float C1 = PA1 + LA1 + 0.5f * (P0 * L2 - P2 * L0);
  float C2 = PA2 + LA2 + 0.5f * (P1 * L2 - P2 * L1);

  if (p0 <= 999) {
#pragma unroll
    for (int i = 0; i < 4; ++i) {
      int p = p0 + i;
      if (p > 999) break;
      float n0 = bp0 + zs[p * 3 + 0] * scale;
      float n1 = bp1 + zs[p * 3 + 1] * scale;
      float n2 = bp2 + zs[p * 3 + 2] * scale;
      C0 += 0.5f * (bp0 * n1 - bp1 * n0);
      C1 += 0.5f * (bp0 * n2 - bp2 * n0);
      C2 += 0.5f * (bp1 * n2 - bp2 * n1);
      bp0 = n0; bp1 = n1; bp2 = n2;
      if (p % 50 == 0) {
        int s = p / 50;
        Cs[s][0] = C0; Cs[s][1] = C1; Cs[s][2] = C2;
      }
      int k = myfe[i];
      if (k >= 0) {
        earr[k][0] = bp0; earr[k][1] = bp1; earr[k][2] = bp2;
        earr[k][3] = C0;  earr[k][4] = C1;  earr[k][5] = C2;
      }
    }
  }
  __syncthreads();

  if (tid < 63) {
    int s = sidx[tid];
    half8 v = {};
    v[0] = (f16)earr[tid][0]; v[1] = (f16)earr[tid][1]; v[2] = (f16)earr[tid][2];
    v[3] = (f16)(earr[tid][3] - Cs[s][0]);
    v[4] = (f16)(earr[tid][4] - Cs[s][1]);
    v[5] = (f16)(earr[tid][5] - Cs[s][2]);
    half8 zz = {};
    half8* d = (half8*)(lsh + ((size_t)(tid + 1) * BATCH + b) * 64);
    d[0] = v;
#pragma unroll
    for (int q = 1; q < 8; ++q) d[q] = zz;
  } else if (tid == 63) {
    half8 zz = {};
    half8* d = (half8*)(lsh + (size_t)b * 64);
#pragma unroll
    for (int q = 0; q < 8; ++q) d[q] = zz;
  }
}

// ---------------------------------------------------------------------------
// f32 -> f16 weight convert with K zero-padding.
// ---------------------------------------------------------------------------
__global__ __launch_bounds__(256)
void cvt_w(const float* __restrict__ src, ushort* __restrict__ dst,
           int N, int Ks, int Kd) {
  int i = blockIdx.x * 256 + threadIdx.x;
  int nblk = Kd >> 3;
  if (i >= N * nblk) return;
  int row = i / nblk, k = (i - row * nblk) * 8;
  half8 v;
#pragma unroll
  for (int j = 0; j < 8; ++j) {
    int kk = k + j;
    float f = (kk < Ks) ? src[(size_t)row * Ks + kk] : 0.f;
    v[j] = (f16)f;
  }
  *(half8*)&dst[(size_t)row * Kd + k] = v;
}

// ---------------------------------------------------------------------------
// Persistent cooperative chain: ALL gated steps in ONE launch.
// 64 blocks x 512 thr = 16 rowgroups(64 rows) x 4 colgroups(128 cols);
// 8 waves = 2(row)x4(col) 32x32 sub-tiles. X staged in 64KB XOR-swizzled
// LDS; W streams from global (L2 stays hot across the whole chain — no
// kernel boundaries). grid.sync() between layers. K-order identical to r5.
// ---------------------------------------------------------------------------
__global__ __launch_bounds__(512, 1)
void chain_coop(const ushort* __restrict__ lsh,
                const ushort* __restrict__ W1h,   // [512][576]
                const ushort* __restrict__ W2h,   // [512][512]
                const ushort* __restrict__ W3h,   // [512][512]
                const float* __restrict__ b1,
                const float* __restrict__ b2,
                const float* __restrict__ b3,
                ushort* __restrict__ Hg,          // [n][1024][512]
                ushort* __restrict__ a1buf,       // [1024][512]
                ushort* __restrict__ a2buf,       // [1024][512]
                GSteps gs) {
  cg::grid_group grid = cg::this_grid();
  __shared__ ushort Xs[64 * 512];                 // 64KB
  char* const xb = (char*)Xs;
  const int tid = threadIdx.x;
  const int wv = tid >> 6, ln = tid & 63;
  const int l15 = ln & 15, l4 = ln >> 4;
  const int rg = blockIdx.x >> 2, cgp = blockIdx.x & 3;
  const int rb = rg * 64;
  const int wr = wv >> 2, wc = wv & 3;            // 2 x 4 waves
  const int colb = cgp * 128 + wc * 32;           // wave col base

  f32x4 acc[2][2];

  // stage 64 rows x 512 cols from SRC (row-major, ld=512) into swizzled LDS
#define STAGE(SRC)                                                            \
  do {                                                                        \
    for (int i = tid; i < 4096; i += 512) {                                   \
      int r = i >> 6, gq = i & 63;                                            \
      half8 v = *(const half8*)((SRC) + (size_t)(rb + r) * HID + gq * 8);     \
      *(half8*)(xb + (size_t)r * 1024 + ((gq ^ (r & 7)) << 4)) = v;           \
    }                                                                         \
  } while (0)

#define MFMA_KS(WPTR, LDW)                                                    \
  do {                                                                        \
    half8 xf[2], wf[2];                                                       \
    _Pragma("unroll")                                                         \
    for (int mi = 0; mi < 2; ++mi) {                                          \
      int r = wr * 32 + mi * 16 + l15;                                        \
      int kg = ks * 4 + l4;                                                   \
      xf[mi] = *(const half8*)(xb + (size_t)r * 1024 + ((kg ^ (r & 7)) << 4));\
    }                                                                         \
    _Pragma("unroll")                                                         \
    for (int ni = 0; ni < 2; ++ni)                                            \
      wf[ni] = *(const half8*)((WPTR) + (size_t)(colb + ni * 16 + l15) * (LDW)\
                               + ks * 32 + l4 * 8);                           \
    _Pragma("unroll")                                                         \
    for (int mi = 0; mi < 2; ++mi)                                            \
      _Pragma("unroll")                                                       \
      for (int ni = 0; ni < 2; ++ni)                                          \
        acc[mi][ni] = __builtin_amdgcn_mfma_f32_16x16x32_f16(                 \
            wf[ni], xf[mi], acc[mi][ni], 0, 0, 0);                            \
  } while (0)

#define EPI(ACT, BIAS, OUTP)                                                  \
  do {                                                                        \
    _Pragma("unroll")                                                         \
    for (int mi = 0; mi < 2; ++mi) {                                          \
      int r = wr * 32 + mi * 16 + l15;                                        \
      _Pragma("unroll")                                                       \
      for (int ni = 0; ni < 2; ++ni) {                                        \
        int c = colb + ni * 16 + l4 * 4;                                      \
        float4 bv = *(const float4*)&(BIAS)[c];                               \
        union { f16 h[4]; ushort4 u; } cv;                                    \
        float bb[4] = {bv.x, bv.y, bv.z, bv.w};                               \
        _Pragma("unroll")                                                     \
        for (int j4 = 0; j4 < 4; ++j4) {                                      \
          float v = acc[mi][ni][j4] + bb[j4];                                 \
          if (ACT == 1) v = fmaxf(v, 0.f);                                    \
          else { float xc = fminf(fmaxf(v, -9.f), 9.f);                       \
                 float e = __expf(2.f * xc); v = (e - 1.f) / (e + 1.f); }     \
          cv.h[j4] = (f16)v;                                                  \
        }                                                                     \
        *(ushort4*)((OUTP) + (size_t)(rb + r) * HID + c) = cv.u;              \
      }                                                                       \
    }                                                                         \
  } while (0)

  for (int j = 0; j < gs.n; ++j) {
    const int g = gs.g[j];
    // ---------------- layer 1: [h | ls_g] @ W1^T, relu -> a1buf ----------
    if (j > 0) STAGE(Hg + (size_t)(j - 1) * (BATCH * HID));
    __syncthreads();
#pragma unroll
    for (int mi = 0; mi < 2; ++mi)
#pragma unroll
      for (int ni = 0; ni < 2; ++ni) acc[mi][ni] = (f32x4){0.f, 0.f, 0.f, 0.f};
    if (j > 0) {
#pragma unroll 4
      for (int ks = 0; ks < 16; ++ks) MFMA_KS(W1h, 576);
    }
#pragma unroll
    for (int kt = 0; kt < 2; ++kt) {      // ls tail: k in [512,576)
      half8 xf[2], wf[2];
#pragma unroll
      for (int mi = 0; mi < 2; ++mi)
        xf[mi] = *(const half8*)(lsh + ((size_t)g * BATCH + rb + wr * 32 + mi * 16 + l15) * 64
                                 + kt * 32 + l4 * 8);
#pragma unroll
      for (int ni = 0; ni < 2; ++ni)
        wf[ni] = *(const half8*)(W1h + (size_t)(colb + ni * 16 + l15) * 576
                                 + 512 + kt * 32 + l4 * 8);
#pragma unroll
      for (int mi = 0; mi < 2; ++mi)
#pragma unroll
        for (int ni = 0; ni < 2; ++ni)
          acc[mi][ni] = __builtin_amdgcn_mfma_f32_16x16x32_f16(
              wf[ni], xf[mi], acc[mi][ni], 0, 0, 0);
    }
    EPI(1, b1, a1buf);
    __threadfence();
    grid.sync();
    // ---------------- layer 2: relu -> a2buf ----------
    STAGE(a1buf);
    __syncthreads();
#pragma unroll
    for (int mi = 0; mi < 2; ++mi)
#pragma unroll
      for (int ni = 0; ni < 2; ++ni) acc[mi][ni] = (f32x4){0.f, 0.f, 0.f, 0.f};
#pragma unroll 4
    for (int ks = 0; ks < 16; ++ks) MFMA_KS(W2h, 512);
    EPI(1, b2, a2buf);
    __threadfence();
    grid.sync();
    // ---------------- layer 3: tanh -> Hg[j] ----------
    STAGE(a2buf);
    __syncthreads();
#pragma unroll
    for (int mi = 0; mi < 2; ++mi)
#pragma unroll
      for (int ni = 0; ni < 2; ++ni) acc[mi][ni] = (f32x4){0.f, 0.f, 0.f, 0.f};
#pragma unroll 4
    for (int ks = 0; ks < 16; ++ks) MFMA_KS(W3h, 512);
    EPI(2, b3, Hg + (size_t)j * (BATCH * HID));
    __threadfence();
    grid.sync();
  }
#undef STAGE
#undef MFMA_KS
#undef EPI
}

// ---------------------------------------------------------------------------
// fp16 MFMA GEMM (parallel phase, validated r2-5): 128x128 tile, BK=64.
// ---------------------------------------------------------------------------
template<int ACT, int L1>
__global__ __launch_bounds__(256)
void gemm_h(const ushort* __restrict__ A, int lda, int nk,
            const ushort* __restrict__ Hg, const ushort* __restrict__ zeroh,
            const ushort* __restrict__ lsh, TList tl, SegMap seg,
            const ushort* __restrict__ W, int ldw,
            const float* __restrict__ bias,
            ushort* __restrict__ C, int ldc) {
  __shared__ ushort lds[16384];
  char* ldsb = (char*)lds;
  const int tid = threadIdx.x;
  const int wv = tid >> 6, ln = tid & 63;
  const int bn0 = blockIdx.x * 128;
  const int br = blockIdx.y;
  const size_t gr0 = (size_t)br * 128;

  const ushort* abase = A;
  const ushort* lbase = nullptr;
  if (L1) {
    int t = tl.t[br >> 3];
    int sj = seg.idx[t];
    abase = (sj < 0) ? zeroh : Hg + (size_t)sj * (BATCH * HID);
    lbase = lsh + (size_t)t * BATCH * 64;
  }

  f32x4 acc[4][4];
#pragma unroll
  for (int mi = 0; mi < 4; ++mi)
#pragma unroll
    for (int ni = 0; ni < 4; ++ni) acc[mi][ni] = (f32x4){0.f, 0.f, 0.f, 0.f};

  const int xr0 = (wv >> 1) * 64, nr0 = (wv & 1) * 64;
  const int l15 = ln & 15, l4 = ln >> 4;

  for (int kt = 0; kt < nk; ++kt) {
#pragma unroll
    for (int i = 0; i < 4; ++i) {
      int q = (i * 4 + wv) * 64 + ln;
      int r = q >> 3, sl = q & 7, ss = sl ^ (r & 7);
      const ushort* src;
      if (L1) {
        int b_ = ((br & 7) << 7) + r;
        if (kt < 8) src = abase + (size_t)b_ * HID + kt * 64 + ss * 8;
        else        src = lbase + (size_t)b_ * 64 + ss * 8;
      } else {
        src = A + (gr0 + r) * (size_t)lda + kt * 64 + ss * 8;
      }
      __builtin_amdgcn_global_load_lds(
          (const __attribute__((address_space(1))) unsigned int*)src,
          (__attribute__((address_space(3))) unsigned int*)(ldsb + (i * 4 + wv) * 1024),
          16, 0, 0);
    }
#pragma unroll
    for (int i = 0; i < 4; ++i) {
      int q = (i * 4 + wv) * 64 + ln;
      int r = q >> 3, sl = q & 7, ss = sl ^ (r & 7);
      const ushort* src = W + (size_t)(bn0 + r) * ldw + kt * 64 + ss * 8;
      __builtin_amdgcn_global_load_lds(
          (const __attribute__((address_space(1))) unsigned int*)src,
          (__attribute__((address_space(3))) unsigned int*)(ldsb + 16384 + (i * 4 + wv) * 1024),
          16, 0, 0);
    }
    __syncthreads();
#pragma unroll
    for (int kk = 0; kk < 2; ++kk) {
      half8 xf[4], wf[4];
#pragma unroll
      for (int mi = 0; mi < 4; ++mi) {
        int r = xr0 + mi * 16 + l15;
        int ss = (kk * 4 + l4) ^ (r & 7);
        xf[mi] = *(const half8*)(ldsb + r * 128 + ss * 16);
      }
#pragma unroll
      for (int ni = 0; ni < 4; ++ni) {
        int r = nr0 + ni * 16 + l15;
        int ss = (kk * 4 + l4) ^ (r & 7);
        wf[ni] = *(const half8*)(ldsb + 16384 + r * 128 + ss * 16);
      }
#pragma unroll
      for (int mi = 0; mi < 4; ++mi)
#pragma unroll
        for (int ni = 0; ni < 4; ++ni)
          acc[mi][ni] = __builtin_amdgcn_mfma_f32_16x16x32_f16(wf[ni], xf[mi], acc[mi][ni], 0, 0, 0);
    }
    __syncthreads();
  }
#pragma unroll
  for (int mi = 0; mi < 4; ++mi) {
    size_t gm = gr0 + xr0 + mi * 16 + l15;
#pragma unroll
    for (int ni = 0; ni < 4; ++ni) {
      int gn = bn0 + nr0 + ni * 16 + l4 * 4;
      f32x4 a = acc[mi][ni];
      union { f16 h[4]; ushort4 u; } cv;
#pragma unroll
      for (int j = 0; j < 4; ++j) {
        float v = a[j] + bias[gn + j];
        if (ACT == 1) v = fmaxf(v, 0.f);
        else { float xc = fminf(fmaxf(v, -9.f), 9.f); float e = __expf(2.f * xc); v = (e - 1.f) / (e + 1.f); }
        cv.h[j] = (f16)v;
      }
      *(ushort4*)&C[gm * ldc + gn] = cv.u;
    }
  }
}

// ---------------------------------------------------------------------------
// out[b, t, :] over ALL 64 t: h source picked per-t (Hg slot or A2h slot).
// ---------------------------------------------------------------------------
__global__ __launch_bounds__(256)
void out_k(const ushort* __restrict__ Hg, const ushort* __restrict__ A2h,
           const float* __restrict__ Wout, float* __restrict__ out, HTab tab) {
  const int tid = threadIdx.x;
  const int lane4 = tid & 3;
  const int row = blockIdx.x * 64 + (tid >> 2);   // t*1024 + b
  const int t = row >> 10, b = row & 1023;
  const int hv = tab.v[t];
  const ushort* base = (hv < 64) ? (Hg + (size_t)hv * (BATCH * HID))
                                 : (A2h + (size_t)(hv - 64) * (BATCH * HID));
  const ushort* hb = base + (size_t)b * HID;
  float a0 = 0.f, a1 = 0.f, a2 = 0.f;
#pragma unroll 4
  for (int q = 0; q < 16; ++q) {
    int k = (q * 4 + lane4) * 8;
    half8 hv8 = *(const half8*)&hb[k];
#pragma unroll
    for (int j = 0; j < 8; ++j) {
      float h = (float)hv8[j];
      a0 += h * Wout[k + j];
      a1 += h * Wout[512 + k + j];
      a2 += h * Wout[1024 + k + j];
    }
  }
  a0 += __shfl_xor(a0, 1); a0 += __shfl_xor(a0, 2);
  a1 += __shfl_xor(a1, 1); a1 += __shfl_xor(a1, 2);
  a2 += __shfl_xor(a2, 1); a2 += __shfl_xor(a2, 2);
  if (lane4 == 0) {
    float* o = out + ((size_t)b * WIN + t) * 3;
    o[0] = a0; o[1] = a1; o[2] = a2;
  }
}

// ---------------------------------------------------------------------------
extern "C" void kernel_launch(void* const* d_in, const int* in_sizes, int n_in,
                              void* d_out, int out_size, void* d_ws, size_t ws_size,
                              hipStream_t stream) {
  (void)n_in; (void)out_size; (void)ws_size; (void)in_sizes;
  const float* z    = (const float*)d_in[0];
  const float* W1   = (const float*)d_in[1];
  const float* b1   = (const float*)d_in[2];
  const float* W2   = (const float*)d_in[3];
  const float* b2   = (const float*)d_in[4];
  const float* W3   = (const float*)d_in[5];
  const float* b3   = (const float*)d_in[6];
  const float* Wout = (const float*)d_in[7];
  float* out = (float*)d_out;

  // ---- replicate _static_schedule exactly (numpy linspace doubles) ----
  double tb[1000], tt[64], tu[20];
  {
    double sb = 1.0 / 999.0; for (int i = 0; i < 1000; ++i) tb[i] = i * sb; tb[999] = 1.0;
    double st = 1.0 / 63.0;  for (int k = 0; k < 64; ++k)  tt[k] = k * st;  tt[63] = 1.0;
    for (int j = 0; j < 20; ++j) tu[j] = tb[50 * j];
  }
  auto ssr = [](const double* a, int n, double v) -> int {
    int lo = 0, hi = n;
    while (lo < hi) { int mid = (lo + hi) >> 1; if (a[mid] <= v) lo = mid + 1; else hi = mid; }
    return lo - 1;
  };
  Sched sc; int gates[64];
  {
    int u_indices[20];
    for (int j = 0; j < 20; ++j) u_indices[j] = ssr(tb, 1000, tu[j]);
    double u_times[80]; int nut = 0; int last = -1;
    for (int k = 1; k < 64; ++k) {
      int it = ssr(tb, 1000, tt[k]);
      int iu = ssr(tu, 20, tt[k]); if (iu < 0) iu = 0;
      if (iu != last) { u_times[nut++] = tu[iu]; last = iu; }
      sc.starts[k - 1] = u_indices[iu];
      sc.ends[k - 1] = it;
    }
    u_times[nut++] = tt[63];
    int qh = 0;
    for (int k = 0; k < 64; ++k) {
      if (qh < nut && tt[k] >= u_times[qh]) { ++qh; gates[k] = 1; } else gates[k] = 0;
    }
  }
  // seg map, gated list, recompute list, out-table
  SegMap seg; GSteps gst; TList tl; HTab tab;
  int ng = 0, nrc = 0, jlast = -1;
  for (int t = 0; t < WIN; ++t) {
    seg.idx[t] = jlast;
    if (gates[t]) {
      if (ng < 32) gst.g[ng] = t;
      tab.v[t] = ng;                // h_t == Hg[ng]
      jlast = ng; ++ng;
    } else {
      tab.v[t] = 64 + nrc;          // h_t == A2h slot nrc
      tl.t[nrc++] = t;
    }
  }
  gst.n = ng;
  for (int i = nrc; i < 64; ++i) tl.t[i] = 0;

  // ---- workspace carve ----
  char* p = (char*)d_ws;
  int* fe      = (int*)p;    p += 1024 * 4;
  int* sidx    = (int*)p;    p += 64 * 4;
  ushort* Hg16 = (ushort*)p; p += (size_t)24 * BATCH * HID * 2;        // 25 MB
  ushort* zeroh= (ushort*)p; p += (size_t)BATCH * HID * 2;             // 1 MB
  ushort* a1b  = (ushort*)p; p += (size_t)BATCH * HID * 2;             // 1 MB
  ushort* a2b  = (ushort*)p; p += (size_t)BATCH * HID * 2;             // 1 MB
  ushort* lsh  = (ushort*)p; p += (size_t)WIN * BATCH * 64 * 2;        // 8.4 MB
  ushort* W1h  = (ushort*)p; p += (size_t)HID * 576 * 2;
  ushort* W2h  = (ushort*)p; p += (size_t)HID * HID * 2;
  ushort* W3h  = (ushort*)p; p += (size_t)HID * HID * 2;
  ushort* A2h  = (ushort*)p; p += (size_t)WIN * BATCH * HID * 2;       // 67 MB
  ushort* A3h  = (ushort*)p; p += (size_t)WIN * BATCH * HID * 2;       // 67 MB

  hipMemsetAsync(zeroh, 0, (size_t)BATCH * HID * 2, stream);

  float scale = (float)std::sqrt(1.0 / 999.0);
  build_flags<<<1, 1024, 0, stream>>>(fe, sidx, sc);
  logsig_scan<<<BATCH, 256, 0, stream>>>(z, fe, sidx, lsh, scale);
  cvt_w<<<(HID * 72 + 255) / 256, 256, 0, stream>>>(W1, W1h, HID, KIN, 576);
  cvt_w<<<(HID * 64 + 255) / 256, 256, 0, stream>>>(W2, W2h, HID, HID, HID);
  cvt_w<<<(HID * 64 + 255) / 256, 256, 0, stream>>>(W3, W3h, HID, HID, HID);

  // ---- persistent cooperative chain: ONE launch for all gated steps ----
  {
    const ushort* lsh_c = lsh; const ushort* w1c = W1h; const ushort* w2c = W2h;
    const ushort* w3c = W3h;
    void* args[] = {(void*)&lsh_c, (void*)&w1c, (void*)&w2c, (void*)&w3c,
                    (void*)&b1, (void*)&b2, (void*)&b3,
                    (void*)&Hg16, (void*)&a1b, (void*)&a2b, (void*)&gst};
    hipLaunchCooperativeKernel((const void*)chain_coop, dim3(64), dim3(512),
                               args, 0, stream);
  }

  // ---- parallel recompute of the non-gated timesteps only ----
  dim3 gg(4, nrc * 8), gb(256);
  gemm_h<1, 1><<<gg, gb, 0, stream>>>(A2h, HID, 9, Hg16, zeroh, lsh, tl, seg,
                                      W1h, 576, b1, A2h, HID);
  gemm_h<1, 0><<<gg, gb, 0, stream>>>(A2h, HID, 8, Hg16, zeroh, lsh, tl, seg,
                                      W2h, HID, b2, A3h, HID);
  gemm_h<2, 0><<<gg, gb, 0, stream>>>(A3h, HID, 8, Hg16, zeroh, lsh, tl, seg,
                                      W3h, HID, b3, A2h, HID);
  out_k<<<WIN * BATCH / 64, 256, 0, stream>>>(Hg16, A2h, Wout, out, tab);
}

// Round 7
// 1589.067 us; speedup vs baseline: 1.6976x; 1.6976x over previous
//
#include <hip/hip_runtime.h>
#include <cmath>

#define WIN 64
#define HID 512
#define BATCH 1024
#define KIN 518

typedef _Float16 f16;
typedef _Float16 half8 __attribute__((ext_vector_type(8)));
typedef float f32x4 __attribute__((ext_vector_type(4)));

struct Sched { int starts[63]; int ends[63]; };
struct SegMap { int idx[64]; };
struct GSteps { int g[32]; int n; };
struct TList { int t[64]; };
struct HTab { int v[64]; };

// ---------------------------------------------------------------------------
// Builder: dense per-position flag tables for the scan kernel.
// ---------------------------------------------------------------------------
__global__ __launch_bounds__(1024)
void build_flags(int* __restrict__ fe, int* __restrict__ sidx, Sched sc) {
  int tid = threadIdx.x;
  if (tid < 1000) fe[tid] = -1;
  __syncthreads();
  if (tid < 63) {
    fe[sc.ends[tid]] = tid;
    sidx[tid] = sc.starts[tid] / 50;
  }
}

// ---------------------------------------------------------------------------
// Parallel logsig scan (validated round 3). Writes lsh[t][b][64] fp16.
// ---------------------------------------------------------------------------
__global__ __launch_bounds__(256)
void logsig_scan(const float* __restrict__ z, const int* __restrict__ fe,
                 const int* __restrict__ sidx, ushort* __restrict__ lsh,
                 float scale) {
  __shared__ float zs[3000];
  __shared__ float Cs[20][3];
  __shared__ float wtot[4][6];
  __shared__ float earr[63][6];
  const int tid = threadIdx.x;
  const int b = blockIdx.x;
  const int ln = tid & 63, wv = tid >> 6;

  const float4* zrow = (const float4*)(z + (size_t)b * 3000);
  for (int i = tid; i < 750; i += 256) ((float4*)zs)[i] = zrow[i];
  if (tid == 0) { Cs[0][0] = 0.f; Cs[0][1] = 0.f; Cs[0][2] = 0.f; }

  const int p0 = 4 * tid + 1;
  int myfe[4];
#pragma unroll
  for (int i = 0; i < 4; ++i) myfe[i] = (p0 + i <= 999) ? fe[p0 + i] : -1;
  __syncthreads();

  float d0 = 0.f, d1 = 0.f, d2 = 0.f, A0 = 0.f, A1 = 0.f, A2 = 0.f;
  if (p0 <= 999) {
    float b0 = 0.f, b1 = 0.f, b2 = 0.f;
#pragma unroll
    for (int i = 0; i < 4; ++i) {
      int p = p0 + i;
      if (p > 999) break;
      float n0 = b0 + zs[p * 3 + 0] * scale;
      float n1 = b1 + zs[p * 3 + 1] * scale;
      float n2 = b2 + zs[p * 3 + 2] * scale;
      A0 += 0.5f * (b0 * n1 - b1 * n0);
      A1 += 0.5f * (b0 * n2 - b2 * n0);
      A2 += 0.5f * (b1 * n2 - b2 * n1);
      b0 = n0; b1 = n1; b2 = n2;
    }
    d0 = b0; d1 = b1; d2 = b2;
  }

#pragma unroll
  for (int off = 1; off < 64; off <<= 1) {
    float e0 = __shfl(d0, ln - off), e1 = __shfl(d1, ln - off), e2 = __shfl(d2, ln - off);
    float eA0 = __shfl(A0, ln - off), eA1 = __shfl(A1, ln - off), eA2 = __shfl(A2, ln - off);
    if (ln >= off) {
      A0 = eA0 + A0 + 0.5f * (e0 * d1 - e1 * d0);
      A1 = eA1 + A1 + 0.5f * (e0 * d2 - e2 * d0);
      A2 = eA2 + A2 + 0.5f * (e1 * d2 - e2 * d1);
      d0 += e0; d1 += e1; d2 += e2;
    }
  }
  if (ln == 63) {
    wtot[wv][0] = d0; wtot[wv][1] = d1; wtot[wv][2] = d2;
    wtot[wv][3] = A0; wtot[wv][4] = A1; wtot[wv][5] = A2;
  }
  __syncthreads();

  float P0 = 0.f, P1 = 0.f, P2 = 0.f, PA0 = 0.f, PA1 = 0.f, PA2 = 0.f;
  for (int w = 0; w < wv; ++w) {
    float t0 = wtot[w][0], t1 = wtot[w][1], t2 = wtot[w][2];
    PA0 = PA0 + wtot[w][3] + 0.5f * (P0 * t1 - P1 * t0);
    PA1 = PA1 + wtot[w][4] + 0.5f * (P0 * t2 - P2 * t0);
    PA2 = PA2 + wtot[w][5] + 0.5f * (P1 * t2 - P2 * t1);
    P0 += t0; P1 += t1; P2 += t2;
  }
  float L0 = __shfl(d0, ln - 1), L1 = __shfl(d1, ln - 1), L2 = __shfl(d2, ln - 1);
  float LA0 = __shfl(A0, ln - 1), LA1 = __shfl(A1, ln - 1), LA2 = __shfl(A2, ln - 1);
  if (ln == 0) { L0 = L1 = L2 = LA0 = LA1 = LA2 = 0.f; }
  float bp0 = P0 + L0, bp1 = P1 + L1, bp2 = P2 + L2;
  float C0 = PA0 + LA0 + 0.5f * (P0 * L1 - P1 * L0);
  float C1 = PA1 + LA1 + 0.5f * (P0 * L2 - P2 * L0);
  float C2 = PA2 + LA2 + 0.5f * (P1 * L2 - P2 * L1);

  if (p0 <= 999) {
#pragma unroll
    for (int i = 0; i < 4; ++i) {
      int p = p0 + i;
      if (p > 999) break;
      float n0 = bp0 + zs[p * 3 + 0] * scale;
      float n1 = bp1 + zs[p * 3 + 1] * scale;
      float n2 = bp2 + zs[p * 3 + 2] * scale;
      C0 += 0.5f * (bp0 * n1 - bp1 * n0);
      C1 += 0.5f * (bp0 * n2 - bp2 * n0);
      C2 += 0.5f * (bp1 * n2 - bp2 * n1);
      bp0 = n0; bp1 = n1; bp2 = n2;
      if (p % 50 == 0) {
        int s = p / 50;
        Cs[s][0] = C0; Cs[s][1] = C1; Cs[s][2] = C2;
      }
      int k = myfe[i];
      if (k >= 0) {
        earr[k][0] = bp0; earr[k][1] = bp1; earr[k][2] = bp2;
        earr[k][3] = C0;  earr[k][4] = C1;  earr[k][5] = C2;
      }
    }
  }
  __syncthreads();

  if (tid < 63) {
    int s = sidx[tid];
    half8 v = {};
    v[0] = (f16)earr[tid][0]; v[1] = (f16)earr[tid][1]; v[2] = (f16)earr[tid][2];
    v[3] = (f16)(earr[tid][3] - Cs[s][0]);
    v[4] = (f16)(earr[tid][4] - Cs[s][1]);
    v[5] = (f16)(earr[tid][5] - Cs[s][2]);
    half8 zz = {};
    half8* d = (half8*)(lsh + ((size_t)(tid + 1) * BATCH + b) * 64);
    d[0] = v;
#pragma unroll
    for (int q = 1; q < 8; ++q) d[q] = zz;
  } else if (tid == 63) {
    half8 zz = {};
    half8* d = (half8*)(lsh + (size_t)b * 64);
#pragma unroll
    for (int q = 0; q < 8; ++q) d[q] = zz;
  }
}

// ---------------------------------------------------------------------------
// f32 -> f16 weight convert with K zero-padding.
// ---------------------------------------------------------------------------
__global__ __launch_bounds__(256)
void cvt_w(const float* __restrict__ src, ushort* __restrict__ dst,
           int N, int Ks, int Kd) {
  int i = blockIdx.x * 256 + threadIdx.x;
  int nblk = Kd >> 3;
  if (i >= N * nblk) return;
  int row = i / nblk, k = (i - row * nblk) * 8;
  half8 v;
#pragma unroll
  for (int j = 0; j < 8; ++j) {
    int kk = k + j;
    float f = (kk < Ks) ? src[(size_t)row * Ks + kk] : 0.f;
    v[j] = (f16)f;
  }
  *(half8*)&dst[(size_t)row * Kd + k] = v;
}

// ---------------------------------------------------------------------------
// Persistent chain with GROUP-LOCAL flag barriers (no cooperative launch).
// 64 blocks = 16 row-groups x 4 col-blocks; data flow couples only the 4
// col-blocks of a group, so each group barriers independently: monotonic
// per-group counter, agent-scope atomics + threadfence (G16 pattern).
// Data layout / MFMA / EPI identical to r6's chain_coop (passed validation).
// ---------------------------------------------------------------------------
__global__ __launch_bounds__(512, 1)
void chain_flag(const ushort* __restrict__ lsh,
                const ushort* __restrict__ W1h,   // [512][576]
                const ushort* __restrict__ W2h,   // [512][512]
                const ushort* __restrict__ W3h,   // [512][512]
                const float* __restrict__ b1,
                const float* __restrict__ b2,
                const float* __restrict__ b3,
                ushort* __restrict__ Hg,          // [n][1024][512]
                ushort* __restrict__ a1buf,       // [1024][512]
                ushort* __restrict__ a2buf,       // [1024][512]
                int* __restrict__ cnt,            // [16], zeroed
                GSteps gs) {
  __shared__ ushort Xs[64 * 512];                 // 64KB
  char* const xb = (char*)Xs;
  const int tid = threadIdx.x;
  const int wv = tid >> 6, ln = tid & 63;
  const int l15 = ln & 15, l4 = ln >> 4;
  const int rg = blockIdx.x >> 2, cgp = blockIdx.x & 3;
  const int rb = rg * 64;
  const int wr = wv >> 2, wc = wv & 3;            // 2 x 4 waves
  const int colb = cgp * 128 + wc * 32;           // wave col base
  int barno = 0;                                  // barriers completed

  f32x4 acc[2][2];

#define GBAR()                                                                \
  do {                                                                        \
    ++barno;                                                                  \
    __syncthreads();                                                          \
    if (tid == 0) {                                                           \
      __threadfence();                                                        \
      __hip_atomic_fetch_add(&cnt[rg], 1, __ATOMIC_RELEASE,                   \
                             __HIP_MEMORY_SCOPE_AGENT);                       \
      while (__hip_atomic_load(&cnt[rg], __ATOMIC_ACQUIRE,                    \
                               __HIP_MEMORY_SCOPE_AGENT) < 4 * barno)         \
        __builtin_amdgcn_s_sleep(1);                                          \
    }                                                                         \
    __syncthreads();                                                          \
    __threadfence();                                                          \
  } while (0)

#define STAGE(SRC)                                                            \
  do {                                                                        \
    for (int i = tid; i < 4096; i += 512) {                                   \
      int r = i >> 6, gq = i & 63;                                            \
      half8 v = *(const half8*)((SRC) + (size_t)(rb + r) * HID + gq * 8);     \
      *(half8*)(xb + (size_t)r * 1024 + ((gq ^ (r & 7)) << 4)) = v;           \
    }                                                                         \
  } while (0)

#define MFMA_KS(WPTR, LDW)                                                    \
  do {                                                                        \
    half8 xf[2], wf[2];                                                       \
    _Pragma("unroll")                                                         \
    for (int mi = 0; mi < 2; ++mi) {                                          \
      int r = wr * 32 + mi * 16 + l15;                                        \
      int kg = ks * 4 + l4;                                                   \
      xf[mi] = *(const half8*)(xb + (size_t)r * 1024 + ((kg ^ (r & 7)) << 4));\
    }                                                                         \
    _Pragma("unroll")                                                         \
    for (int ni = 0; ni < 2; ++ni)                                            \
      wf[ni] = *(const half8*)((WPTR) + (size_t)(colb + ni * 16 + l15) * (LDW)\
                               + ks * 32 + l4 * 8);                           \
    _Pragma("unroll")                                                         \
    for (int mi = 0; mi < 2; ++mi)                                            \
      _Pragma("unroll")                                                       \
      for (int ni = 0; ni < 2; ++ni)                                          \
        acc[mi][ni] = __builtin_amdgcn_mfma_f32_16x16x32_f16(                 \
            wf[ni], xf[mi], acc[mi][ni], 0, 0, 0);                            \
  } while (0)

#define EPI(ACT, BIAS, OUTP)                                                  \
  do {                                                                        \
    _Pragma("unroll")                                                         \
    for (int mi = 0; mi < 2; ++mi) {                                          \
      int r = wr * 32 + mi * 16 + l15;                                        \
      _Pragma("unroll")                                                       \
      for (int ni = 0; ni < 2; ++ni) {                                        \
        int c = colb + ni * 16 + l4 * 4;                                      \
        float4 bv = *(const float4*)&(BIAS)[c];                               \
        union { f16 h[4]; ushort4 u; } cv;                                    \
        float bb[4] = {bv.x, bv.y, bv.z, bv.w};                               \
        _Pragma("unroll")                                                     \
        for (int j4 = 0; j4 < 4; ++j4) {                                      \
          float v = acc[mi][ni][j4] + bb[j4];                                 \
          if (ACT == 1) v = fmaxf(v, 0.f);                                    \
          else { float xc = fminf(fmaxf(v, -9.f), 9.f);                       \
                 float e = __expf(2.f * xc); v = (e - 1.f) / (e + 1.f); }     \
          cv.h[j4] = (f16)v;                                                  \
        }                                                                     \
        *(ushort4*)((OUTP) + (size_t)(rb + r) * HID + c) = cv.u;              \
      }                                                                       \
    }                                                                         \
  } while (0)

  for (int j = 0; j < gs.n; ++j) {
    const int g = gs.g[j];
    // ---------------- layer 1: [h | ls_g] @ W1^T, relu -> a1buf ----------
    if (j > 0) STAGE(Hg + (size_t)(j - 1) * (BATCH * HID));
    __syncthreads();
#pragma unroll
    for (int mi = 0; mi < 2; ++mi)
#pragma unroll
      for (int ni = 0; ni < 2; ++ni) acc[mi][ni] = (f32x4){0.f, 0.f, 0.f, 0.f};
    if (j > 0) {
#pragma unroll 4
      for (int ks = 0; ks < 16; ++ks) MFMA_KS(W1h, 576);
    }
#pragma unroll
    for (int kt = 0; kt < 2; ++kt) {      // ls tail: k in [512,576)
      half8 xf[2], wf[2];
#pragma unroll
      for (int mi = 0; mi < 2; ++mi)
        xf[mi] = *(const half8*)(lsh + ((size_t)g * BATCH + rb + wr * 32 + mi * 16 + l15) * 64
                                 + kt * 32 + l4 * 8);
#pragma unroll
      for (int ni = 0; ni < 2; ++ni)
        wf[ni] = *(const half8*)(W1h + (size_t)(colb + ni * 16 + l15) * 576
                                 + 512 + kt * 32 + l4 * 8);
#pragma unroll
      for (int mi = 0; mi < 2; ++mi)
#pragma unroll
        for (int ni = 0; ni < 2; ++ni)
          acc[mi][ni] = __builtin_amdgcn_mfma_f32_16x16x32_f16(
              wf[ni], xf[mi], acc[mi][ni], 0, 0, 0);
    }
    EPI(1, b1, a1buf);
    GBAR();
    // ---------------- layer 2: relu -> a2buf ----------
    STAGE(a1buf);
    __syncthreads();
#pragma unroll
    for (int mi = 0; mi < 2; ++mi)
#pragma unroll
      for (int ni = 0; ni < 2; ++ni) acc[mi][ni] = (f32x4){0.f, 0.f, 0.f, 0.f};
#pragma unroll 4
    for (int ks = 0; ks < 16; ++ks) MFMA_KS(W2h, 512);
    EPI(1, b2, a2buf);
    GBAR();
    // ---------------- layer 3: tanh -> Hg[j] ----------
    STAGE(a2buf);
    __syncthreads();
#pragma unroll
    for (int mi = 0; mi < 2; ++mi)
#pragma unroll
      for (int ni = 0; ni < 2; ++ni) acc[mi][ni] = (f32x4){0.f, 0.f, 0.f, 0.f};
#pragma unroll 4
    for (int ks = 0; ks < 16; ++ks) MFMA_KS(W3h, 512);
    EPI(2, b3, Hg + (size_t)j * (BATCH * HID));
    GBAR();
  }
#undef GBAR
#undef STAGE
#undef MFMA_KS
#undef EPI
}

// ---------------------------------------------------------------------------
// fp16 MFMA GEMM (parallel phase, validated r2-6): 128x128 tile, BK=64.
// ---------------------------------------------------------------------------
template<int ACT, int L1>
__global__ __launch_bounds__(256)
void gemm_h(const ushort* __restrict__ A, int lda, int nk,
            const ushort* __restrict__ Hg, const ushort* __restrict__ zeroh,
            const ushort* __restrict__ lsh, TList tl, SegMap seg,
            const ushort* __restrict__ W, int ldw,
            const float* __restrict__ bias,
            ushort* __restrict__ C, int ldc) {
  __shared__ ushort lds[16384];
  char* ldsb = (char*)lds;
  const int tid = threadIdx.x;
  const int wv = tid >> 6, ln = tid & 63;
  const int bn0 = blockIdx.x * 128;
  const int br = blockIdx.y;
  const size_t gr0 = (size_t)br * 128;

  const ushort* abase = A;
  const ushort* lbase = nullptr;
  if (L1) {
    int t = tl.t[br >> 3];
    int sj = seg.idx[t];
    abase = (sj < 0) ? zeroh : Hg + (size_t)sj * (BATCH * HID);
    lbase = lsh + (size_t)t * BATCH * 64;
  }

  f32x4 acc[4][4];
#pragma unroll
  for (int mi = 0; mi < 4; ++mi)
#pragma unroll
    for (int ni = 0; ni < 4; ++ni) acc[mi][ni] = (f32x4){0.f, 0.f, 0.f, 0.f};

  const int xr0 = (wv >> 1) * 64, nr0 = (wv & 1) * 64;
  const int l15 = ln & 15, l4 = ln >> 4;

  for (int kt = 0; kt < nk; ++kt) {
#pragma unroll
    for (int i = 0; i < 4; ++i) {
      int q = (i * 4 + wv) * 64 + ln;
      int r = q >> 3, sl = q & 7, ss = sl ^ (r & 7);
      const ushort* src;
      if (L1) {
        int b_ = ((br & 7) << 7) + r;
        if (kt < 8) src = abase + (size_t)b_ * HID + kt * 64 + ss * 8;
        else        src = lbase + (size_t)b_ * 64 + ss * 8;
      } else {
        src = A + (gr0 + r) * (size_t)lda + kt * 64 + ss * 8;
      }
      __builtin_amdgcn_global_load_lds(
          (const __attribute__((address_space(1))) unsigned int*)src,
          (__attribute__((address_space(3))) unsigned int*)(ldsb + (i * 4 + wv) * 1024),
          16, 0, 0);
    }
#pragma unroll
    for (int i = 0; i < 4; ++i) {
      int q = (i * 4 + wv) * 64 + ln;
      int r = q >> 3, sl = q & 7, ss = sl ^ (r & 7);
      const ushort* src = W + (size_t)(bn0 + r) * ldw + kt * 64 + ss * 8;
      __builtin_amdgcn_global_load_lds(
          (const __attribute__((address_space(1))) unsigned int*)src,
          (__attribute__((address_space(3))) unsigned int*)(ldsb + 16384 + (i * 4 + wv) * 1024),
          16, 0, 0);
    }
    __syncthreads();
#pragma unroll
    for (int kk = 0; kk < 2; ++kk) {
      half8 xf[4], wf[4];
#pragma unroll
      for (int mi = 0; mi < 4; ++mi) {
        int r = xr0 + mi * 16 + l15;
        int ss = (kk * 4 + l4) ^ (r & 7);
        xf[mi] = *(const half8*)(ldsb + r * 128 + ss * 16);
      }
#pragma unroll
      for (int ni = 0; ni < 4; ++ni) {
        int r = nr0 + ni * 16 + l15;
        int ss = (kk * 4 + l4) ^ (r & 7);
        wf[ni] = *(const half8*)(ldsb + 16384 + r * 128 + ss * 16);
      }
#pragma unroll
      for (int mi = 0; mi < 4; ++mi)
#pragma unroll
        for (int ni = 0; ni < 4; ++ni)
          acc[mi][ni] = __builtin_amdgcn_mfma_f32_16x16x32_f16(wf[ni], xf[mi], acc[mi][ni], 0, 0, 0);
    }
    __syncthreads();
  }
#pragma unroll
  for (int mi = 0; mi < 4; ++mi) {
    size_t gm = gr0 + xr0 + mi * 16 + l15;
#pragma unroll
    for (int ni = 0; ni < 4; ++ni) {
      int gn = bn0 + nr0 + ni * 16 + l4 * 4;
      f32x4 a = acc[mi][ni];
      union { f16 h[4]; ushort4 u; } cv;
#pragma unroll
      for (int j = 0; j < 4; ++j) {
        float v = a[j] + bias[gn + j];
        if (ACT == 1) v = fmaxf(v, 0.f);
        else { float xc = fminf(fmaxf(v, -9.f), 9.f); float e = __expf(2.f * xc); v = (e - 1.f) / (e + 1.f); }
        cv.h[j] = (f16)v;
      }
      *(ushort4*)&C[gm * ldc + gn] = cv.u;
    }
  }
}

// ---------------------------------------------------------------------------
// out[b, t, :] over ALL 64 t: h source picked per-t (Hg slot or A2h slot).
// ---------------------------------------------------------------------------
__global__ __launch_bounds__(256)
void out_k(const ushort* __restrict__ Hg, const ushort* __restrict__ A2h,
           const float* __restrict__ Wout, float* __restrict__ out, HTab tab) {
  const int tid = threadIdx.x;
  const int lane4 = tid & 3;
  const int row = blockIdx.x * 64 + (tid >> 2);   // t*1024 + b
  const int t = row >> 10, b = row & 1023;
  const int hv = tab.v[t];
  const ushort* base = (hv < 64) ? (Hg + (size_t)hv * (BATCH * HID))
                                 : (A2h + (size_t)(hv - 64) * (BATCH * HID));
  const ushort* hb = base + (size_t)b * HID;
  float a0 = 0.f, a1 = 0.f, a2 = 0.f;
#pragma unroll 4
  for (int q = 0; q < 16; ++q) {
    int k = (q * 4 + lane4) * 8;
    half8 hv8 = *(const half8*)&hb[k];
#pragma unroll
    for (int j = 0; j < 8; ++j) {
      float h = (float)hv8[j];
      a0 += h * Wout[k + j];
      a1 += h * Wout[512 + k + j];
      a2 += h * Wout[1024 + k + j];
    }
  }
  a0 += __shfl_xor(a0, 1); a0 += __shfl_xor(a0, 2);
  a1 += __shfl_xor(a1, 1); a1 += __shfl_xor(a1, 2);
  a2 += __shfl_xor(a2, 1); a2 += __shfl_xor(a2, 2);
  if (lane4 == 0) {
    float* o = out + ((size_t)b * WIN + t) * 3;
    o[0] = a0; o[1] = a1; o[2] = a2;
  }
}

// ---------------------------------------------------------------------------
extern "C" void kernel_launch(void* const* d_in, const int* in_sizes, int n_in,
                              void* d_out, int out_size, void* d_ws, size_t ws_size,
                              hipStream_t stream) {
  (void)n_in; (void)out_size; (void)ws_size; (void)in_sizes;
  const float* z    = (const float*)d_in[0];
  const float* W1   = (const float*)d_in[1];
  const float* b1   = (const float*)d_in[2];
  const float* W2   = (const float*)d_in[3];
  const float* b2   = (const float*)d_in[4];
  const float* W3   = (const float*)d_in[5];
  const float* b3   = (const float*)d_in[6];
  const float* Wout = (const float*)d_in[7];
  float* out = (float*)d_out;

  // ---- replicate _static_schedule exactly (numpy linspace doubles) ----
  double tb[1000], tt[64], tu[20];
  {
    double sb = 1.0 / 999.0; for (int i = 0; i < 1000; ++i) tb[i] = i * sb; tb[999] = 1.0;
    double st = 1.0 / 63.0;  for (int k = 0; k < 64; ++k)  tt[k] = k * st;  tt[63] = 1.0;
    for (int j = 0; j < 20; ++j) tu[j] = tb[50 * j];
  }
  auto ssr = [](const double* a, int n, double v) -> int {
    int lo = 0, hi = n;
    while (lo < hi) { int mid = (lo + hi) >> 1; if (a[mid] <= v) lo = mid + 1; else hi = mid; }
    return lo - 1;
  };
  Sched sc; int gates[64];
  {
    int u_indices[20];
    for (int j = 0; j < 20; ++j) u_indices[j] = ssr(tb, 1000, tu[j]);
    double u_times[80]; int nut = 0; int last = -1;
    for (int k = 1; k < 64; ++k) {
      int it = ssr(tb, 1000, tt[k]);
      int iu = ssr(tu, 20, tt[k]); if (iu < 0) iu = 0;
      if (iu != last) { u_times[nut++] = tu[iu]; last = iu; }
      sc.starts[k - 1] = u_indices[iu];
      sc.ends[k - 1] = it;
    }
    u_times[nut++] = tt[63];
    int qh = 0;
    for (int k = 0; k < 64; ++k) {
      if (qh < nut && tt[k] >= u_times[qh]) { ++qh; gates[k] = 1; } else gates[k] = 0;
    }
  }
  // seg map, gated list, recompute list, out-table
  SegMap seg; GSteps gst; TList tl; HTab tab;
  int ng = 0, nrc = 0, jlast = -1;
  for (int t = 0; t < WIN; ++t) {
    seg.idx[t] = jlast;
    if (gates[t]) {
      if (ng < 32) gst.g[ng] = t;
      tab.v[t] = ng;                // h_t == Hg[ng]
      jlast = ng; ++ng;
    } else {
      tab.v[t] = 64 + nrc;          // h_t == A2h slot nrc
      tl.t[nrc++] = t;
    }
  }
  gst.n = ng;
  for (int i = nrc; i < 64; ++i) tl.t[i] = 0;

  // ---- workspace carve ----
  char* p = (char*)d_ws;
  int* fe      = (int*)p;    p += 1024 * 4;
  int* sidx    = (int*)p;    p += 64 * 4;
  int* cnt     = (int*)p;    p += 64 * 4;                              // barrier flags
  ushort* Hg16 = (ushort*)p; p += (size_t)24 * BATCH * HID * 2;        // 25 MB
  ushort* zeroh= (ushort*)p; p += (size_t)BATCH * HID * 2;             // 1 MB
  ushort* a1b  = (ushort*)p; p += (size_t)BATCH * HID * 2;             // 1 MB
  ushort* a2b  = (ushort*)p; p += (size_t)BATCH * HID * 2;             // 1 MB
  ushort* lsh  = (ushort*)p; p += (size_t)WIN * BATCH * 64 * 2;        // 8.4 MB
  ushort* W1h  = (ushort*)p; p += (size_t)HID * 576 * 2;
  ushort* W2h  = (ushort*)p; p += (size_t)HID * HID * 2;
  ushort* W3h  = (ushort*)p; p += (size_t)HID * HID * 2;
  ushort* A2h  = (ushort*)p; p += (size_t)WIN * BATCH * HID * 2;       // 67 MB
  ushort* A3h  = (ushort*)p; p += (size_t)WIN * BATCH * HID * 2;       // 67 MB

  hipMemsetAsync(zeroh, 0, (size_t)BATCH * HID * 2, stream);
  hipMemsetAsync(cnt, 0, 64 * 4, stream);

  float scale = (float)std::sqrt(1.0 / 999.0);
  build_flags<<<1, 1024, 0, stream>>>(fe, sidx, sc);
  logsig_scan<<<BATCH, 256, 0, stream>>>(z, fe, sidx, lsh, scale);
  cvt_w<<<(HID * 72 + 255) / 256, 256, 0, stream>>>(W1, W1h, HID, KIN, 576);
  cvt_w<<<(HID * 64 + 255) / 256, 256, 0, stream>>>(W2, W2h, HID, HID, HID);
  cvt_w<<<(HID * 64 + 255) / 256, 256, 0, stream>>>(W3, W3h, HID, HID, HID);

  // ---- persistent chain, group-local flag barriers, ONE launch ----
  chain_flag<<<64, 512, 0, stream>>>(lsh, W1h, W2h, W3h, b1, b2, b3,
                                     Hg16, a1b, a2b, cnt, gst);

  // ---- parallel recompute of the non-gated timesteps only ----
  dim3 gg(4, nrc * 8), gb(256);
  gemm_h<1, 1><<<gg, gb, 0, stream>>>(A2h, HID, 9, Hg16, zeroh, lsh, tl, seg,
                                      W1h, 576, b1, A2h, HID);
  gemm_h<1, 0><<<gg, gb, 0, stream>>>(A2h, HID, 8, Hg16, zeroh, lsh, tl, seg,
                                      W2h, HID, b2, A3h, HID);
  gemm_h<2, 0><<<gg, gb, 0, stream>>>(A3h, HID, 8, Hg16, zeroh, lsh, tl, seg,
                                      W3h, HID, b3, A2h, HID);
  out_k<<<WIN * BATCH / 64, 256, 0, stream>>>(Hg16, A2h, Wout, out, tab);
}

// Round 8
// 927.828 us; speedup vs baseline: 2.9074x; 1.7127x over previous
//
#include <hip/hip_runtime.h>
#include <cmath>

#define WIN 64
#define HID 512
#define BATCH 1024
#define KIN 518

typedef _Float16 f16;
typedef _Float16 half8 __attribute__((ext_vector_type(8)));
typedef float f32x4 __attribute__((ext_vector_type(4)));

struct Sched { int starts[63]; int ends[63]; };
struct TL { int t[8]; };

// ---------------------------------------------------------------------------
// Builder: dense per-position flag tables for the scan kernel.
// ---------------------------------------------------------------------------
__global__ __launch_bounds__(1024)
void build_flags(int* __restrict__ fe, int* __restrict__ sidx, Sched sc) {
  int tid = threadIdx.x;
  if (tid < 1000) fe[tid] = -1;
  __syncthreads();
  if (tid < 63) {
    fe[sc.ends[tid]] = tid;
    sidx[tid] = sc.starts[tid] / 50;
  }
}

// ---------------------------------------------------------------------------
// Parallel logsig scan (validated round 3). Writes lsh[t][b][64] fp16.
// ---------------------------------------------------------------------------
__global__ __launch_bounds__(256)
void logsig_scan(const float* __restrict__ z, const int* __restrict__ fe,
                 const int* __restrict__ sidx, ushort* __restrict__ lsh,
                 float scale) {
  __shared__ float zs[3000];
  __shared__ float Cs[20][3];
  __shared__ float wtot[4][6];
  __shared__ float earr[63][6];
  const int tid = threadIdx.x;
  const int b = blockIdx.x;
  const int ln = tid & 63, wv = tid >> 6;

  const float4* zrow = (const float4*)(z + (size_t)b * 3000);
  for (int i = tid; i < 750; i += 256) ((float4*)zs)[i] = zrow[i];
  if (tid == 0) { Cs[0][0] = 0.f; Cs[0][1] = 0.f; Cs[0][2] = 0.f; }

  const int p0 = 4 * tid + 1;
  int myfe[4];
#pragma unroll
  for (int i = 0; i < 4; ++i) myfe[i] = (p0 + i <= 999) ? fe[p0 + i] : -1;
  __syncthreads();

  float d0 = 0.f, d1 = 0.f, d2 = 0.f, A0 = 0.f, A1 = 0.f, A2 = 0.f;
  if (p0 <= 999) {
    float b0 = 0.f, b1 = 0.f, b2 = 0.f;
#pragma unroll
    for (int i = 0; i < 4; ++i) {
      int p = p0 + i;
      if (p > 999) break;
      float n0 = b0 + zs[p * 3 + 0] * scale;
      float n1 = b1 + zs[p * 3 + 1] * scale;
      float n2 = b2 + zs[p * 3 + 2] * scale;
      A0 += 0.5f * (b0 * n1 - b1 * n0);
      A1 += 0.5f * (b0 * n2 - b2 * n0);
      A2 += 0.5f * (b1 * n2 - b2 * n1);
      b0 = n0; b1 = n1; b2 = n2;
    }
    d0 = b0; d1 = b1; d2 = b2;
  }

#pragma unroll
  for (int off = 1; off < 64; off <<= 1) {
    float e0 = __shfl(d0, ln - off), e1 = __shfl(d1, ln - off), e2 = __shfl(d2, ln - off);
    float eA0 = __shfl(A0, ln - off), eA1 = __shfl(A1, ln - off), eA2 = __shfl(A2, ln - off);
    if (ln >= off) {
      A0 = eA0 + A0 + 0.5f * (e0 * d1 - e1 * d0);
      A1 = eA1 + A1 + 0.5f * (e0 * d2 - e2 * d0);
      A2 = eA2 + A2 + 0.5f * (e1 * d2 - e2 * d1);
      d0 += e0; d1 += e1; d2 += e2;
    }
  }
  if (ln == 63) {
    wtot[wv][0] = d0; wtot[wv][1] = d1; wtot[wv][2] = d2;
    wtot[wv][3] = A0; wtot[wv][4] = A1; wtot[wv][5] = A2;
  }
  __syncthreads();

  float P0 = 0.f, P1 = 0.f, P2 = 0.f, PA0 = 0.f, PA1 = 0.f, PA2 = 0.f;
  for (int w = 0; w < wv; ++w) {
    float t0 = wtot[w][0], t1 = wtot[w][1], t2 = wtot[w][2];
    PA0 = PA0 + wtot[w][3] + 0.5f * (P0 * t1 - P1 * t0);
    PA1 = PA1 + wtot[w][4] + 0.5f * (P0 * t2 - P2 * t0);
    PA2 = PA2 + wtot[w][5] + 0.5f * (P1 * t2 - P2 * t1);
    P0 += t0; P1 += t1; P2 += t2;
  }
  float L0 = __shfl(d0, ln - 1), L1 = __shfl(d1, ln - 1), L2 = __shfl(d2, ln - 1);
  float LA0 = __shfl(A0, ln - 1), LA1 = __shfl(A1, ln - 1), LA2 = __shfl(A2, ln - 1);
  if (ln == 0) { L0 = L1 = L2 = LA0 = LA1 = LA2 = 0.f; }
  float bp0 = P0 + L0, bp1 = P1 + L1, bp2 = P2 + L2;
  float C0 = PA0 + LA0 + 0.5f * (P0 * L1 - P1 * L0);
  float C1 = PA1 + LA1 + 0.5f * (P0 * L2 - P2 * L0);
  float C2 = PA2 + LA2 + 0.5f * (P1 * L2 - P2 * L1);

  if (p0 <= 999) {
#pragma unroll
    for (int i = 0; i < 4; ++i) {
      int p = p0 + i;
      if (p > 999) break;
      float n0 = bp0 + zs[p * 3 + 0] * scale;
      float n1 = bp1 + zs[p * 3 + 1] * scale;
      float n2 = bp2 + zs[p * 3 + 2] * scale;
      C0 += 0.5f * (bp0 * n1 - bp1 * n0);
      C1 += 0.5f * (bp0 * n2 - bp2 * n0);
      C2 += 0.5f * (bp1 * n2 - bp2 * n1);
      bp0 = n0; bp1 = n1; bp2 = n2;
      if (p % 50 == 0) {
        int s = p / 50;
        Cs[s][0] = C0; Cs[s][1] = C1; Cs[s][2] = C2;
      }
      int k = myfe[i];
      if (k >= 0) {
        earr[k][0] = bp0; earr[k][1] = bp1; earr[k][2] = bp2;
        earr[k][3] = C0;  earr[k][4] = C1;  earr[k][5] = C2;
      }
    }
  }
  __syncthreads();

  if (tid < 63) {
    int s = sidx[tid];
    half8 v = {};
    v[0] = (f16)earr[tid][0]; v[1] = (f16)earr[tid][1]; v[2] = (f16)earr[tid][2];
    v[3] = (f16)(earr[tid][3] - Cs[s][0]);
    v[4] = (f16)(earr[tid][4] - Cs[s][1]);
    v[5] = (f16)(earr[tid][5] - Cs[s][2]);
    half8 zz = {};
    half8* d = (half8*)(lsh + ((size_t)(tid + 1) * BATCH + b) * 64);
    d[0] = v;
#pragma unroll
    for (int q = 1; q < 8; ++q) d[q] = zz;
  } else if (tid == 63) {
    half8 zz = {};
    half8* d = (half8*)(lsh + (size_t)b * 64);
#pragma unroll
    for (int q = 0; q < 8; ++q) d[q] = zz;
  }
}

// ---------------------------------------------------------------------------
// f32 -> f16 weight convert with K zero-padding.
// ---------------------------------------------------------------------------
__global__ __launch_bounds__(256)
void cvt_w(const float* __restrict__ src, ushort* __restrict__ dst,
           int N, int Ks, int Kd) {
  int i = blockIdx.x * 256 + threadIdx.x;
  int nblk = Kd >> 3;
  if (i >= N * nblk) return;
  int row = i / nblk, k = (i - row * nblk) * 8;
  half8 v;
#pragma unroll
  for (int j = 0; j < 8; ++j) {
    int kk = k + j;
    float f = (kk < Ks) ? src[(size_t)row * Ks + kk] : 0.f;
    v[j] = (f16)f;
  }
  *(half8*)&dst[(size_t)row * Kd + k] = v;
}

// ---------------------------------------------------------------------------
// Per-round fp16 MFMA GEMM (from validated gemm_h): 128x128 tile, BK=64,
// 4 waves (2x2), 16x16x32 f16 MFMA, global_load_lds staging + XOR swizzle.
// Round semantics: grid.y = n_t*8 block-rows; slot s = br>>3, t = tl.t[s].
//  L1=1 : X rows b=(br&7)*128+r come from carry[b] (kt<8) and lsh[t][b] (kt=8).
//  L1=0 : X rows from A at br*128 (act buffer, slot-contiguous).
//  SCAT=1: C row = t*1024 + (br&7)*128 + .. (scatter to Hall[t]); else br*128.
// ---------------------------------------------------------------------------
template<int ACT, int L1, int SCAT>
__global__ __launch_bounds__(256)
void gemm_r(const ushort* __restrict__ A,
            const ushort* __restrict__ carry,
            const ushort* __restrict__ lsh,
            TL tl, int nk,
            const ushort* __restrict__ W, int ldw,
            const float* __restrict__ bias,
            ushort* __restrict__ C) {
  __shared__ ushort lds[16384];
  char* ldsb = (char*)lds;
  const int tid = threadIdx.x;
  const int wv = tid >> 6, ln = tid & 63;
  const int bn0 = blockIdx.x * 128;
  const int br = blockIdx.y;
  const int t = tl.t[br >> 3];
  const size_t gr0 = (size_t)br * 128;
  const ushort* lbase = lsh + (size_t)t * BATCH * 64;

  f32x4 acc[4][4];
#pragma unroll
  for (int mi = 0; mi < 4; ++mi)
#pragma unroll
    for (int ni = 0; ni < 4; ++ni) acc[mi][ni] = (f32x4){0.f, 0.f, 0.f, 0.f};

  const int xr0 = (wv >> 1) * 64, nr0 = (wv & 1) * 64;
  const int l15 = ln & 15, l4 = ln >> 4;

  for (int kt = 0; kt < nk; ++kt) {
    // ---- stage X tile ----
#pragma unroll
    for (int i = 0; i < 4; ++i) {
      int q = (i * 4 + wv) * 64 + ln;
      int r = q >> 3, sl = q & 7, ss = sl ^ (r & 7);
      const ushort* src;
      if (L1) {
        int b_ = ((br & 7) << 7) + r;
        if (kt < 8) src = carry + (size_t)b_ * HID + kt * 64 + ss * 8;
        else        src = lbase + (size_t)b_ * 64 + ss * 8;
      } else {
        src = A + (gr0 + r) * (size_t)HID + kt * 64 + ss * 8;
      }
      __builtin_amdgcn_global_load_lds(
          (const __attribute__((address_space(1))) unsigned int*)src,
          (__attribute__((address_space(3))) unsigned int*)(ldsb + (i * 4 + wv) * 1024),
          16, 0, 0);
    }
    // ---- stage W tile ----
#pragma unroll
    for (int i = 0; i < 4; ++i) {
      int q = (i * 4 + wv) * 64 + ln;
      int r = q >> 3, sl = q & 7, ss = sl ^ (r & 7);
      const ushort* src = W + (size_t)(bn0 + r) * ldw + kt * 64 + ss * 8;
      __builtin_amdgcn_global_load_lds(
          (const __attribute__((address_space(1))) unsigned int*)src,
          (__attribute__((address_space(3))) unsigned int*)(ldsb + 16384 + (i * 4 + wv) * 1024),
          16, 0, 0);
    }
    __syncthreads();
#pragma unroll
    for (int kk = 0; kk < 2; ++kk) {
      half8 xf[4], wf[4];
#pragma unroll
      for (int mi = 0; mi < 4; ++mi) {
        int r = xr0 + mi * 16 + l15;
        int ss = (kk * 4 + l4) ^ (r & 7);
        xf[mi] = *(const half8*)(ldsb + r * 128 + ss * 16);
      }
#pragma unroll
      for (int ni = 0; ni < 4; ++ni) {
        int r = nr0 + ni * 16 + l15;
        int ss = (kk * 4 + l4) ^ (r & 7);
        wf[ni] = *(const half8*)(ldsb + 16384 + r * 128 + ss * 16);
      }
#pragma unroll
      for (int mi = 0; mi < 4; ++mi)
#pragma unroll
        for (int ni = 0; ni < 4; ++ni)
          acc[mi][ni] = __builtin_amdgcn_mfma_f32_16x16x32_f16(wf[ni], xf[mi], acc[mi][ni], 0, 0, 0);
    }
    __syncthreads();
  }
  // ---- epilogue: bias + act + f16 pack, 8B stores ----
#pragma unroll
  for (int mi = 0; mi < 4; ++mi) {
    size_t gm;
    if (SCAT) gm = (size_t)t * BATCH + ((br & 7) << 7) + xr0 + mi * 16 + l15;
    else      gm = gr0 + xr0 + mi * 16 + l15;
#pragma unroll
    for (int ni = 0; ni < 4; ++ni) {
      int gn = bn0 + nr0 + ni * 16 + l4 * 4;
      f32x4 a = acc[mi][ni];
      union { f16 h[4]; ushort4 u; } cv;
#pragma unroll
      for (int j = 0; j < 4; ++j) {
        float v = a[j] + bias[gn + j];
        if (ACT == 1) v = fmaxf(v, 0.f);
        else { float xc = fminf(fmaxf(v, -9.f), 9.f); float e = __expf(2.f * xc); v = (e - 1.f) / (e + 1.f); }
        cv.h[j] = (f16)v;
      }
      *(ushort4*)&C[gm * HID + gn] = cv.u;
    }
  }
}

// ---------------------------------------------------------------------------
// out[b, t, :] = Hall[t][b][:] @ Wout^T. 4 lanes per row, shfl reduce.
// ---------------------------------------------------------------------------
__global__ __launch_bounds__(256)
void out_k(const ushort* __restrict__ Hall, const float* __restrict__ Wout,
           float* __restrict__ out) {
  const int tid = threadIdx.x;
  const int lane4 = tid & 3;
  const int row = blockIdx.x * 64 + (tid >> 2);   // t*1024 + b
  const int t = row >> 10, b = row & 1023;
  const ushort* hb = Hall + (size_t)row * HID;
  float a0 = 0.f, a1 = 0.f, a2 = 0.f;
#pragma unroll 4
  for (int q = 0; q < 16; ++q) {
    int k = (q * 4 + lane4) * 8;
    half8 hv8 = *(const half8*)&hb[k];
#pragma unroll
    for (int j = 0; j < 8; ++j) {
      float h = (float)hv8[j];
      a0 += h * Wout[k + j];
      a1 += h * Wout[512 + k + j];
      a2 += h * Wout[1024 + k + j];
    }
  }
  a0 += __shfl_xor(a0, 1); a0 += __shfl_xor(a0, 2);
  a1 += __shfl_xor(a1, 1); a1 += __shfl_xor(a1, 2);
  a2 += __shfl_xor(a2, 1); a2 += __shfl_xor(a2, 2);
  if (lane4 == 0) {
    float* o = out + ((size_t)b * WIN + t) * 3;
    o[0] = a0; o[1] = a1; o[2] = a2;
  }
}

// ---------------------------------------------------------------------------
extern "C" void kernel_launch(void* const* d_in, const int* in_sizes, int n_in,
                              void* d_out, int out_size, void* d_ws, size_t ws_size,
                              hipStream_t stream) {
  (void)n_in; (void)out_size; (void)ws_size; (void)in_sizes;
  const float* z    = (const float*)d_in[0];
  const float* W1   = (const float*)d_in[1];
  const float* b1   = (const float*)d_in[2];
  const float* W2   = (const float*)d_in[3];
  const float* b2   = (const float*)d_in[4];
  const float* W3   = (const float*)d_in[5];
  const float* b3   = (const float*)d_in[6];
  const float* Wout = (const float*)d_in[7];
  float* out = (float*)d_out;

  // ---- replicate _static_schedule exactly (numpy linspace doubles) ----
  double tb[1000], tt[64], tu[20];
  {
    double sb = 1.0 / 999.0; for (int i = 0; i < 1000; ++i) tb[i] = i * sb; tb[999] = 1.0;
    double st = 1.0 / 63.0;  for (int k = 0; k < 64; ++k)  tt[k] = k * st;  tt[63] = 1.0;
    for (int j = 0; j < 20; ++j) tu[j] = tb[50 * j];
  }
  auto ssr = [](const double* a, int n, double v) -> int {
    int lo = 0, hi = n;
    while (lo < hi) { int mid = (lo + hi) >> 1; if (a[mid] <= v) lo = mid + 1; else hi = mid; }
    return lo - 1;
  };
  Sched sc; int gates[64];
  {
    int u_indices[20];
    for (int j = 0; j < 20; ++j) u_indices[j] = ssr(tb, 1000, tu[j]);
    double u_times[80]; int nut = 0; int last = -1;
    for (int k = 1; k < 64; ++k) {
      int it = ssr(tb, 1000, tt[k]);
      int iu = ssr(tu, 20, tt[k]); if (iu < 0) iu = 0;
      if (iu != last) { u_times[nut++] = tu[iu]; last = iu; }
      sc.starts[k - 1] = u_indices[iu];
      sc.ends[k - 1] = it;
    }
    u_times[nut++] = tt[63];
    int qh = 0;
    for (int k = 0; k < 64; ++k) {
      if (qh < nut && tt[k] >= u_times[qh]) { ++qh; gates[k] = 1; } else gates[k] = 0;
    }
  }
  // seg map + gated list + per-round t lists
  int seg[64], g[64], ng = 0, jlast = -1;
  for (int t = 0; t < WIN; ++t) {
    seg[t] = jlast;
    if (gates[t]) { g[ng] = t; jlast = ng; ++ng; }
  }
  // round r (0..ng-1): all t with seg[t] == r-1; carry = Hall[g[r-1]] (r=0: zeros)

  // ---- workspace carve ----
  char* p = (char*)d_ws;
  int* fe      = (int*)p;    p += 1024 * 4;
  int* sidx    = (int*)p;    p += 64 * 4;
  ushort* zeroh= (ushort*)p; p += (size_t)BATCH * HID * 2;             // 1 MB
  ushort* lsh  = (ushort*)p; p += (size_t)WIN * BATCH * 64 * 2;        // 8.4 MB
  ushort* W1h  = (ushort*)p; p += (size_t)HID * 576 * 2;
  ushort* W2h  = (ushort*)p; p += (size_t)HID * HID * 2;
  ushort* W3h  = (ushort*)p; p += (size_t)HID * HID * 2;
  ushort* Hall = (ushort*)p; p += (size_t)WIN * BATCH * HID * 2;       // 67 MB
  ushort* act1 = (ushort*)p; p += (size_t)8 * BATCH * HID * 2;         // 8.4 MB
  ushort* act2 = (ushort*)p; p += (size_t)8 * BATCH * HID * 2;         // 8.4 MB

  hipMemsetAsync(zeroh, 0, (size_t)BATCH * HID * 2, stream);

  float scale = (float)std::sqrt(1.0 / 999.0);
  build_flags<<<1, 1024, 0, stream>>>(fe, sidx, sc);
  logsig_scan<<<BATCH, 256, 0, stream>>>(z, fe, sidx, lsh, scale);
  cvt_w<<<(HID * 72 + 255) / 256, 256, 0, stream>>>(W1, W1h, HID, KIN, 576);
  cvt_w<<<(HID * 64 + 255) / 256, 256, 0, stream>>>(W2, W2h, HID, HID, HID);
  cvt_w<<<(HID * 64 + 255) / 256, 256, 0, stream>>>(W3, W3h, HID, HID, HID);

  // ---- serial per-segment rounds: 3 GEMM launches each ----
  for (int r = 0; r < ng; ++r) {
    TL tlr; int cnt = 0;
    for (int t = 0; t < WIN && cnt < 8; ++t)
      if (seg[t] == r - 1) tlr.t[cnt++] = t;
    if (cnt == 0) continue;
    for (int i = cnt; i < 8; ++i) tlr.t[i] = tlr.t[0];
    const ushort* carry = (r == 0) ? zeroh : Hall + (size_t)g[r - 1] * (BATCH * HID);
    dim3 gg(4, cnt * 8), gb(256);
    gemm_r<1, 1, 0><<<gg, gb, 0, stream>>>(nullptr, carry, lsh, tlr, 9,
                                           W1h, 576, b1, act1);
    gemm_r<1, 0, 0><<<gg, gb, 0, stream>>>(act1, nullptr, lsh, tlr, 8,
                                           W2h, HID, b2, act2);
    gemm_r<2, 0, 1><<<gg, gb, 0, stream>>>(act2, nullptr, lsh, tlr, 8,
                                           W3h, HID, b3, Hall);
  }

  out_k<<<WIN * BATCH / 64, 256, 0, stream>>>(Hall, Wout, out);
}

// Round 9
// 729.723 us; speedup vs baseline: 3.6967x; 1.2715x over previous
//
#include <hip/hip_runtime.h>
#include <cmath>

#define WIN 64
#define HID 512
#define BATCH 1024
#define KIN 518

typedef _Float16 f16;
typedef _Float16 half8 __attribute__((ext_vector_type(8)));
typedef float f32x4 __attribute__((ext_vector_type(4)));

struct Sched { int starts[63]; int ends[63]; };
struct TL { int t[8]; };

// ---------------------------------------------------------------------------
// Parallel logsig scan (validated r3-r8) + in-kernel flag table (was
// build_flags). Writes lsh[t][b][64] fp16.
// ---------------------------------------------------------------------------
__global__ __launch_bounds__(256)
void logsig_scan(const float* __restrict__ z, Sched sc,
                 ushort* __restrict__ lsh, float scale) {
  __shared__ float zs[3000];
  __shared__ float Cs[20][3];
  __shared__ float wtot[4][6];
  __shared__ float earr[63][6];
  __shared__ short fe_s[1000];
  const int tid = threadIdx.x;
  const int b = blockIdx.x;
  const int ln = tid & 63, wv = tid >> 6;

  // stage z row (12 KB, coalesced float4) + init flag table
  const float4* zrow = (const float4*)(z + (size_t)b * 3000);
  for (int i = tid; i < 750; i += 256) ((float4*)zs)[i] = zrow[i];
  for (int i = tid; i < 1000; i += 256) fe_s[i] = -1;
  if (tid == 0) { Cs[0][0] = 0.f; Cs[0][1] = 0.f; Cs[0][2] = 0.f; }
  __syncthreads();
  if (tid < 63) fe_s[sc.ends[tid]] = (short)tid;
  __syncthreads();

  const int p0 = 4 * tid + 1;
  int myfe[4];
#pragma unroll
  for (int i = 0; i < 4; ++i) myfe[i] = (p0 + i <= 999) ? fe_s[p0 + i] : -1;

  float d0 = 0.f, d1 = 0.f, d2 = 0.f, A0 = 0.f, A1 = 0.f, A2 = 0.f;
  if (p0 <= 999) {
    float b0 = 0.f, b1 = 0.f, b2 = 0.f;
#pragma unroll
    for (int i = 0; i < 4; ++i) {
      int p = p0 + i;
      if (p > 999) break;
      float n0 = b0 + zs[p * 3 + 0] * scale;
      float n1 = b1 + zs[p * 3 + 1] * scale;
      float n2 = b2 + zs[p * 3 + 2] * scale;
      A0 += 0.5f * (b0 * n1 - b1 * n0);
      A1 += 0.5f * (b0 * n2 - b2 * n0);
      A2 += 0.5f * (b1 * n2 - b2 * n1);
      b0 = n0; b1 = n1; b2 = n2;
    }
    d0 = b0; d1 = b1; d2 = b2;
  }

#pragma unroll
  for (int off = 1; off < 64; off <<= 1) {
    float e0 = __shfl(d0, ln - off), e1 = __shfl(d1, ln - off), e2 = __shfl(d2, ln - off);
    float eA0 = __shfl(A0, ln - off), eA1 = __shfl(A1, ln - off), eA2 = __shfl(A2, ln - off);
    if (ln >= off) {
      A0 = eA0 + A0 + 0.5f * (e0 * d1 - e1 * d0);
      A1 = eA1 + A1 + 0.5f * (e0 * d2 - e2 * d0);
      A2 = eA2 + A2 + 0.5f * (e1 * d2 - e2 * d1);
      d0 += e0; d1 += e1; d2 += e2;
    }
  }
  if (ln == 63) {
    wtot[wv][0] = d0; wtot[wv][1] = d1; wtot[wv][2] = d2;
    wtot[wv][3] = A0; wtot[wv][4] = A1; wtot[wv][5] = A2;
  }
  __syncthreads();

  float P0 = 0.f, P1 = 0.f, P2 = 0.f, PA0 = 0.f, PA1 = 0.f, PA2 = 0.f;
  for (int w = 0; w < wv; ++w) {
    float t0 = wtot[w][0], t1 = wtot[w][1], t2 = wtot[w][2];
    PA0 = PA0 + wtot[w][3] + 0.5f * (P0 * t1 - P1 * t0);
    PA1 = PA1 + wtot[w][4] + 0.5f * (P0 * t2 - P2 * t0);
    PA2 = PA2 + wtot[w][5] + 0.5f * (P1 * t2 - P2 * t1);
    P0 += t0; P1 += t1; P2 += t2;
  }
  float L0 = __shfl(d0, ln - 1), L1 = __shfl(d1, ln - 1), L2 = __shfl(d2, ln - 1);
  float LA0 = __shfl(A0, ln - 1), LA1 = __shfl(A1, ln - 1), LA2 = __shfl(A2, ln - 1);
  if (ln == 0) { L0 = L1 = L2 = LA0 = LA1 = LA2 = 0.f; }
  float bp0 = P0 + L0, bp1 = P1 + L1, bp2 = P2 + L2;
  float C0 = PA0 + LA0 + 0.5f * (P0 * L1 - P1 * L0);
  float C1 = PA1 + LA1 + 0.5f * (P0 * L2 - P2 * L0);
  float C2 = PA2 + LA2 + 0.5f * (P1 * L2 - P2 * L1);

  if (p0 <= 999) {
#pragma unroll
    for (int i = 0; i < 4; ++i) {
      int p = p0 + i;
      if (p > 999) break;
      float n0 = bp0 + zs[p * 3 + 0] * scale;
      float n1 = bp1 + zs[p * 3 + 1] * scale;
      float n2 = bp2 + zs[p * 3 + 2] * scale;
      C0 += 0.5f * (bp0 * n1 - bp1 * n0);
      C1 += 0.5f * (bp0 * n2 - bp2 * n0);
      C2 += 0.5f * (bp1 * n2 - bp2 * n1);
      bp0 = n0; bp1 = n1; bp2 = n2;
      if (p % 50 == 0) {
        int s = p / 50;
        Cs[s][0] = C0; Cs[s][1] = C1; Cs[s][2] = C2;
      }
      int k = myfe[i];
      if (k >= 0) {
        earr[k][0] = bp0; earr[k][1] = bp1; earr[k][2] = bp2;
        earr[k][3] = C0;  earr[k][4] = C1;  earr[k][5] = C2;
      }
    }
  }
  __syncthreads();

  if (tid < 63) {
    int s = sc.starts[tid] / 50;
    half8 v = {};
    v[0] = (f16)earr[tid][0]; v[1] = (f16)earr[tid][1]; v[2] = (f16)earr[tid][2];
    v[3] = (f16)(earr[tid][3] - Cs[s][0]);
    v[4] = (f16)(earr[tid][4] - Cs[s][1]);
    v[5] = (f16)(earr[tid][5] - Cs[s][2]);
    half8 zz = {};
    half8* d = (half8*)(lsh + ((size_t)(tid + 1) * BATCH + b) * 64);
    d[0] = v;
#pragma unroll
    for (int q = 1; q < 8; ++q) d[q] = zz;
  } else if (tid == 63) {
    half8 zz = {};
    half8* d = (half8*)(lsh + (size_t)b * 64);
#pragma unroll
    for (int q = 0; q < 8; ++q) d[q] = zz;
  }
}

// ---------------------------------------------------------------------------
// One-shot f32 -> f16 convert of all three weight matrices (K zero-padded).
// ---------------------------------------------------------------------------
__global__ __launch_bounds__(256)
void cvt_all(const float* __restrict__ W1, const float* __restrict__ W2,
             const float* __restrict__ W3, ushort* __restrict__ W1h,
             ushort* __restrict__ W2h, ushort* __restrict__ W3h) {
  const int n1 = HID * (576 / 8);                 // 36864 vec8 blocks
  const int n2 = HID * (HID / 8);                 // 32768
  int i = blockIdx.x * 256 + threadIdx.x;
  const float* src; ushort* dst; int Ks, Kd;
  if (i < n1)           { src = W1; dst = W1h; Ks = KIN; Kd = 576; }
  else if (i < n1 + n2) { src = W2; dst = W2h; Ks = HID; Kd = HID; i -= n1; }
  else if (i < n1 + 2 * n2) { src = W3; dst = W3h; Ks = HID; Kd = HID; i -= n1 + n2; }
  else return;
  int nblk = Kd >> 3;
  int row = i / nblk, k = (i - row * nblk) * 8;
  half8 v;
#pragma unroll
  for (int j = 0; j < 8; ++j) {
    int kk = k + j;
    float f = (kk < Ks) ? src[(size_t)row * Ks + kk] : 0.f;
    v[j] = (f16)f;
  }
  *(half8*)&dst[(size_t)row * Kd + k] = v;
}

// ---------------------------------------------------------------------------
// Per-round fp16 MFMA GEMM with 2-PHASE PIPELINE (T3-minimum): double-
// buffered LDS (2 x 32KB), next-kt loads issued BEFORE current-kt compute,
// one barrier per kt. 128x128 tile, BK=64, 4 waves (2x2), 16x16x32 f16.
// Round semantics (validated r8): slot s = br>>3, t = tl.t[s].
//  L1=1 : X rows b=(br&7)*128+r from carry[b] (kt<8) / lsh[t][b] (kt=8).
//  L1=0 : X rows from A at br*128 (act buffer, slot-contiguous).
//  SCAT=1: C row = t*1024 + (br&7)*128 + .. (scatter to Hall[t]).
// ---------------------------------------------------------------------------
template<int ACT, int L1, int SCAT>
__global__ __launch_bounds__(256)
void gemm_r(const ushort* __restrict__ A,
            const ushort* __restrict__ carry,
            const ushort* __restrict__ lsh,
            TL tl, int k0, int nk,
            const ushort* __restrict__ W, int ldw,
            const float* __restrict__ bias,
            ushort* __restrict__ C) {
  __shared__ ushort lds[32768];                   // 64KB: 2 x (X 16K | W 16K)
  char* ldsb = (char*)lds;
  const int tid = threadIdx.x;
  const int wv = tid >> 6, ln = tid & 63;
  const int bn0 = blockIdx.x * 128;
  const int br = blockIdx.y;
  const int t = tl.t[br >> 3];
  const size_t gr0 = (size_t)br * 128;
  const ushort* lbase = lsh + (size_t)t * BATCH * 64;

  // per-thread staging coords (constant across kt)
  const int q = tid;                              // 0..255 -> 4 rows each
  f32x4 acc[4][4];
#pragma unroll
  for (int mi = 0; mi < 4; ++mi)
#pragma unroll
    for (int ni = 0; ni < 4; ++ni) acc[mi][ni] = (f32x4){0.f, 0.f, 0.f, 0.f};

  const int xr0 = (wv >> 1) * 64, nr0 = (wv & 1) * 64;
  const int l15 = ln & 15, l4 = ln >> 4;

#define STAGE(BI, KT)                                                         \
  do {                                                                        \
    _Pragma("unroll")                                                         \
    for (int i = 0; i < 4; ++i) {                                             \
      int qq = (i * 4 + wv) * 64 + ln;                                        \
      int r = qq >> 3, sl = qq & 7, ss = sl ^ (r & 7);                        \
      const ushort* src;                                                      \
      if (L1) {                                                               \
        int b_ = ((br & 7) << 7) + r;                                         \
        if ((KT) < 8) src = carry + (size_t)b_ * HID + (KT) * 64 + ss * 8;    \
        else          src = lbase + (size_t)b_ * 64 + ss * 8;                 \
      } else {                                                                \
        src = A + (gr0 + r) * (size_t)HID + (KT) * 64 + ss * 8;               \
      }                                                                       \
      __builtin_amdgcn_global_load_lds(                                       \
          (const __attribute__((address_space(1))) unsigned int*)src,         \
          (__attribute__((address_space(3))) unsigned int*)                   \
              (ldsb + (BI) * 32768 + (i * 4 + wv) * 1024), 16, 0, 0);         \
    }                                                                         \
    _Pragma("unroll")                                                         \
    for (int i = 0; i < 4; ++i) {                                             \
      int qq = (i * 4 + wv) * 64 + ln;                                        \
      int r = qq >> 3, sl = qq & 7, ss = sl ^ (r & 7);                        \
      const ushort* src = W + (size_t)(bn0 + r) * ldw + (KT) * 64 + ss * 8;   \
      __builtin_amdgcn_global_load_lds(                                       \
          (const __attribute__((address_space(1))) unsigned int*)src,         \
          (__attribute__((address_space(3))) unsigned int*)                   \
              (ldsb + (BI) * 32768 + 16384 + (i * 4 + wv) * 1024), 16, 0, 0); \
    }                                                                         \
  } while (0)

  STAGE(0, k0);
  __syncthreads();                               // vmcnt(0) drained by compiler
  int cur = 0;
  for (int kt = k0; kt < nk; ++kt) {
    if (kt + 1 < nk) STAGE(cur ^ 1, kt + 1);     // overlap: issue before compute
#pragma unroll
    for (int kk = 0; kk < 2; ++kk) {
      half8 xf[4], wf[4];
#pragma unroll
      for (int mi = 0; mi < 4; ++mi) {
        int r = xr0 + mi * 16 + l15;
        int ss = (kk * 4 + l4) ^ (r & 7);
        xf[mi] = *(const half8*)(ldsb + cur * 32768 + r * 128 + ss * 16);
      }
#pragma unroll
      for (int ni = 0; ni < 4; ++ni) {
        int r = nr0 + ni * 16 + l15;
        int ss = (kk * 4 + l4) ^ (r & 7);
        wf[ni] = *(const half8*)(ldsb + cur * 32768 + 16384 + r * 128 + ss * 16);
      }
#pragma unroll
      for (int mi = 0; mi < 4; ++mi)
#pragma unroll
        for (int ni = 0; ni < 4; ++ni)
          acc[mi][ni] = __builtin_amdgcn_mfma_f32_16x16x32_f16(wf[ni], xf[mi], acc[mi][ni], 0, 0, 0);
    }
    __syncthreads();                             // next buf ready + cur reads done
    cur ^= 1;
  }
#undef STAGE

  // ---- epilogue: bias + act + f16 pack, 8B stores ----
#pragma unroll
  for (int mi = 0; mi < 4; ++mi) {
    size_t gm;
    if (SCAT) gm = (size_t)t * BATCH + ((br & 7) << 7) + xr0 + mi * 16 + l15;
    else      gm = gr0 + xr0 + mi * 16 + l15;
#pragma unroll
    for (int ni = 0; ni < 4; ++ni) {
      int gn = bn0 + nr0 + ni * 16 + l4 * 4;
      f32x4 a = acc[mi][ni];
      union { f16 h[4]; ushort4 u; } cv;
#pragma unroll
      for (int j = 0; j < 4; ++j) {
        float v = a[j] + bias[gn + j];
        if (ACT == 1) v = fmaxf(v, 0.f);
        else { float xc = fminf(fmaxf(v, -9.f), 9.f); float e = __expf(2.f * xc); v = (e - 1.f) / (e + 1.f); }
        cv.h[j] = (f16)v;
      }
      *(ushort4*)&C[gm * HID + gn] = cv.u;
    }
  }
}

// ---------------------------------------------------------------------------
// out[b, t, :] = Hall[t][b][:] @ Wout^T. 4 lanes per row, shfl reduce.
// ---------------------------------------------------------------------------
__global__ __launch_bounds__(256)
void out_k(const ushort* __restrict__ Hall, const float* __restrict__ Wout,
           float* __restrict__ out) {
  const int tid = threadIdx.x;
  const int lane4 = tid & 3;
  const int row = blockIdx.x * 64 + (tid >> 2);   // t*1024 + b
  const int t = row >> 10, b = row & 1023;
  const ushort* hb = Hall + (size_t)row * HID;
  float a0 = 0.f, a1 = 0.f, a2 = 0.f;
#pragma unroll 4
  for (int q = 0; q < 16; ++q) {
    int k = (q * 4 + lane4) * 8;
    half8 hv8 = *(const half8*)&hb[k];
#pragma unroll
    for (int j = 0; j < 8; ++j) {
      float h = (float)hv8[j];
      a0 += h * Wout[k + j];
      a1 += h * Wout[512 + k + j];
      a2 += h * Wout[1024 + k + j];
    }
  }
  a0 += __shfl_xor(a0, 1); a0 += __shfl_xor(a0, 2);
  a1 += __shfl_xor(a1, 1); a1 += __shfl_xor(a1, 2);
  a2 += __shfl_xor(a2, 1); a2 += __shfl_xor(a2, 2);
  if (lane4 == 0) {
    float* o = out + ((size_t)b * WIN + t) * 3;
    o[0] = a0; o[1] = a1; o[2] = a2;
  }
}

// ---------------------------------------------------------------------------
extern "C" void kernel_launch(void* const* d_in, const int* in_sizes, int n_in,
                              void* d_out, int out_size, void* d_ws, size_t ws_size,
                              hipStream_t stream) {
  (void)n_in; (void)out_size; (void)ws_size; (void)in_sizes;
  const float* z    = (const float*)d_in[0];
  const float* W1   = (const float*)d_in[1];
  const float* b1   = (const float*)d_in[2];
  const float* W2   = (const float*)d_in[3];
  const float* b2   = (const float*)d_in[4];
  const float* W3   = (const float*)d_in[5];
  const float* b3   = (const float*)d_in[6];
  const float* Wout = (const float*)d_in[7];
  float* out = (float*)d_out;

  // ---- replicate _static_schedule exactly (numpy linspace doubles) ----
  double tb[1000], tt[64], tu[20];
  {
    double sb = 1.0 / 999.0; for (int i = 0; i < 1000; ++i) tb[i] = i * sb; tb[999] = 1.0;
    double st = 1.0 / 63.0;  for (int k = 0; k < 64; ++k)  tt[k] = k * st;  tt[63] = 1.0;
    for (int j = 0; j < 20; ++j) tu[j] = tb[50 * j];
  }
  auto ssr = [](const double* a, int n, double v) -> int {
    int lo = 0, hi = n;
    while (lo < hi) { int mid = (lo + hi) >> 1; if (a[mid] <= v) lo = mid + 1; else hi = mid; }
    return lo - 1;
  };
  Sched sc; int gates[64];
  {
    int u_indices[20];
    for (int j = 0; j < 20; ++j) u_indices[j] = ssr(tb, 1000, tu[j]);
    double u_times[80]; int nut = 0; int last = -1;
    for (int k = 1; k < 64; ++k) {
      int it = ssr(tb, 1000, tt[k]);
      int iu = ssr(tu, 20, tt[k]); if (iu < 0) iu = 0;
      if (iu != last) { u_times[nut++] = tu[iu]; last = iu; }
      sc.starts[k - 1] = u_indices[iu];
      sc.ends[k - 1] = it;
    }
    u_times[nut++] = tt[63];
    int qh = 0;
    for (int k = 0; k < 64; ++k) {
      if (qh < nut && tt[k] >= u_times[qh]) { ++qh; gates[k] = 1; } else gates[k] = 0;
    }
  }
  // seg map + gated list
  int seg[64], g[64], ng = 0, jlast = -1;
  for (int t = 0; t < WIN; ++t) {
    seg[t] = jlast;
    if (gates[t]) { g[ng] = t; jlast = ng; ++ng; }
  }

  // ---- workspace carve ----
  char* p = (char*)d_ws;
  ushort* lsh  = (ushort*)p; p += (size_t)WIN * BATCH * 64 * 2;        // 8.4 MB
  ushort* W1h  = (ushort*)p; p += (size_t)HID * 576 * 2;
  ushort* W2h  = (ushort*)p; p += (size_t)HID * HID * 2;
  ushort* W3h  = (ushort*)p; p += (size_t)HID * HID * 2;
  ushort* Hall = (ushort*)p; p += (size_t)WIN * BATCH * HID * 2;       // 67 MB
  ushort* act1 = (ushort*)p; p += (size_t)8 * BATCH * HID * 2;         // 8.4 MB
  ushort* act2 = (ushort*)p; p += (size_t)8 * BATCH * HID * 2;         // 8.4 MB

  float scale = (float)std::sqrt(1.0 / 999.0);
  logsig_scan<<<BATCH, 256, 0, stream>>>(z, sc, lsh, scale);
  cvt_all<<<(HID * 72 + 2 * HID * 64 + 255) / 256, 256, 0, stream>>>(
      W1, W2, W3, W1h, W2h, W3h);

  // ---- serial per-segment rounds: 3 pipelined GEMM launches each ----
  for (int r = 0; r < ng; ++r) {
    TL tlr; int cnt = 0;
    for (int t = 0; t < WIN && cnt < 8; ++t)
      if (seg[t] == r - 1) tlr.t[cnt++] = t;
    if (cnt == 0) continue;
    for (int i = cnt; i < 8; ++i) tlr.t[i] = tlr.t[0];
    const ushort* carry = (r == 0) ? nullptr : Hall + (size_t)g[r - 1] * (BATCH * HID);
    int k0 = (r == 0) ? 8 : 0;                    // round 0: zero carry, ls only
    dim3 gg(4, cnt * 8), gb(256);
    gemm_r<1, 1, 0><<<gg, gb, 0, stream>>>(nullptr, carry, lsh, tlr, k0, 9,
                                           W1h, 576, b1, act1);
    gemm_r<1, 0, 0><<<gg, gb, 0, stream>>>(act1, nullptr, lsh, tlr, 0, 8,
                                           W2h, HID, b2, act2);
    gemm_r<2, 0, 1><<<gg, gb, 0, stream>>>(act2, nullptr, lsh, tlr, 0, 8,
                                           W3h, HID, b3, Hall);
  }

  out_k<<<WIN * BATCH / 64, 256, 0, stream>>>(Hall, Wout, out);
}

// Round 10
// 714.905 us; speedup vs baseline: 3.7733x; 1.0207x over previous
//
#include <hip/hip_runtime.h>
#include <cmath>

#define WIN 64
#define HID 512
#define BATCH 1024
#define KIN 518

typedef _Float16 f16;
typedef _Float16 half8 __attribute__((ext_vector_type(8)));
typedef float f32x4 __attribute__((ext_vector_type(4)));

struct Sched { int starts[63]; int ends[63]; };
struct TL { int t[8]; };

// ---------------------------------------------------------------------------
// Parallel logsig scan (validated r3-r9) + in-kernel flag table.
// Writes lsh[t][b][64] fp16.
// ---------------------------------------------------------------------------
__global__ __launch_bounds__(256)
void logsig_scan(const float* __restrict__ z, Sched sc,
                 ushort* __restrict__ lsh, float scale) {
  __shared__ float zs[3000];
  __shared__ float Cs[20][3];
  __shared__ float wtot[4][6];
  __shared__ float earr[63][6];
  __shared__ short fe_s[1000];
  const int tid = threadIdx.x;
  const int b = blockIdx.x;
  const int ln = tid & 63, wv = tid >> 6;

  const float4* zrow = (const float4*)(z + (size_t)b * 3000);
  for (int i = tid; i < 750; i += 256) ((float4*)zs)[i] = zrow[i];
  for (int i = tid; i < 1000; i += 256) fe_s[i] = -1;
  if (tid == 0) { Cs[0][0] = 0.f; Cs[0][1] = 0.f; Cs[0][2] = 0.f; }
  __syncthreads();
  if (tid < 63) fe_s[sc.ends[tid]] = (short)tid;
  __syncthreads();

  const int p0 = 4 * tid + 1;
  int myfe[4];
#pragma unroll
  for (int i = 0; i < 4; ++i) myfe[i] = (p0 + i <= 999) ? fe_s[p0 + i] : -1;

  float d0 = 0.f, d1 = 0.f, d2 = 0.f, A0 = 0.f, A1 = 0.f, A2 = 0.f;
  if (p0 <= 999) {
    float b0 = 0.f, b1 = 0.f, b2 = 0.f;
#pragma unroll
    for (int i = 0; i < 4; ++i) {
      int p = p0 + i;
      if (p > 999) break;
      float n0 = b0 + zs[p * 3 + 0] * scale;
      float n1 = b1 + zs[p * 3 + 1] * scale;
      float n2 = b2 + zs[p * 3 + 2] * scale;
      A0 += 0.5f * (b0 * n1 - b1 * n0);
      A1 += 0.5f * (b0 * n2 - b2 * n0);
      A2 += 0.5f * (b1 * n2 - b2 * n1);
      b0 = n0; b1 = n1; b2 = n2;
    }
    d0 = b0; d1 = b1; d2 = b2;
  }

#pragma unroll
  for (int off = 1; off < 64; off <<= 1) {
    float e0 = __shfl(d0, ln - off), e1 = __shfl(d1, ln - off), e2 = __shfl(d2, ln - off);
    float eA0 = __shfl(A0, ln - off), eA1 = __shfl(A1, ln - off), eA2 = __shfl(A2, ln - off);
    if (ln >= off) {
      A0 = eA0 + A0 + 0.5f * (e0 * d1 - e1 * d0);
      A1 = eA1 + A1 + 0.5f * (e0 * d2 - e2 * d0);
      A2 = eA2 + A2 + 0.5f * (e1 * d2 - e2 * d1);
      d0 += e0; d1 += e1; d2 += e2;
    }
  }
  if (ln == 63) {
    wtot[wv][0] = d0; wtot[wv][1] = d1; wtot[wv][2] = d2;
    wtot[wv][3] = A0; wtot[wv][4] = A1; wtot[wv][5] = A2;
  }
  __syncthreads();

  float P0 = 0.f, P1 = 0.f, P2 = 0.f, PA0 = 0.f, PA1 = 0.f, PA2 = 0.f;
  for (int w = 0; w < wv; ++w) {
    float t0 = wtot[w][0], t1 = wtot[w][1], t2 = wtot[w][2];
    PA0 = PA0 + wtot[w][3] + 0.5f * (P0 * t1 - P1 * t0);
    PA1 = PA1 + wtot[w][4] + 0.5f * (P0 * t2 - P2 * t0);
    PA2 = PA2 + wtot[w][5] + 0.5f * (P1 * t2 - P2 * t1);
    P0 += t0; P1 += t1; P2 += t2;
  }
  float L0 = __shfl(d0, ln - 1), L1 = __shfl(d1, ln - 1), L2 = __shfl(d2, ln - 1);
  float LA0 = __shfl(A0, ln - 1), LA1 = __shfl(A1, ln - 1), LA2 = __shfl(A2, ln - 1);
  if (ln == 0) { L0 = L1 = L2 = LA0 = LA1 = LA2 = 0.f; }
  float bp0 = P0 + L0, bp1 = P1 + L1, bp2 = P2 + L2;
  float C0 = PA0 + LA0 + 0.5f * (P0 * L1 - P1 * L0);
  float C1 = PA1 + LA1 + 0.5f * (P0 * L2 - P2 * L0);
  float C2 = PA2 + LA2 + 0.5f * (P1 * L2 - P2 * L1);

  if (p0 <= 999) {
#pragma unroll
    for (int i = 0; i < 4; ++i) {
      int p = p0 + i;
      if (p > 999) break;
      float n0 = bp0 + zs[p * 3 + 0] * scale;
      float n1 = bp1 + zs[p * 3 + 1] * scale;
      float n2 = bp2 + zs[p * 3 + 2] * scale;
      C0 += 0.5f * (bp0 * n1 - bp1 * n0);
      C1 += 0.5f * (bp0 * n2 - bp2 * n0);
      C2 += 0.5f * (bp1 * n2 - bp2 * n1);
      bp0 = n0; bp1 = n1; bp2 = n2;
      if (p % 50 == 0) {
        int s = p / 50;
        Cs[s][0] = C0; Cs[s][1] = C1; Cs[s][2] = C2;
      }
      int k = myfe[i];
      if (k >= 0) {
        earr[k][0] = bp0; earr[k][1] = bp1; earr[k][2] = bp2;
        earr[k][3] = C0;  earr[k][4] = C1;  earr[k][5] = C2;
      }
    }
  }
  __syncthreads();

  if (tid < 63) {
    int s = sc.starts[tid] / 50;
    half8 v = {};
    v[0] = (f16)earr[tid][0]; v[1] = (f16)earr[tid][1]; v[2] = (f16)earr[tid][2];
    v[3] = (f16)(earr[tid][3] - Cs[s][0]);
    v[4] = (f16)(earr[tid][4] - Cs[s][1]);
    v[5] = (f16)(earr[tid][5] - Cs[s][2]);
    half8 zz = {};
    half8* d = (half8*)(lsh + ((size_t)(tid + 1) * BATCH + b) * 64);
    d[0] = v;
#pragma unroll
    for (int q = 1; q < 8; ++q) d[q] = zz;
  } else if (tid == 63) {
    half8 zz = {};
    half8* d = (half8*)(lsh + (size_t)b * 64);
#pragma unroll
    for (int q = 0; q < 8; ++q) d[q] = zz;
  }
}

// ---------------------------------------------------------------------------
// One-shot f32 -> f16 convert of all three weight matrices (K zero-padded).
// ---------------------------------------------------------------------------
__global__ __launch_bounds__(256)
void cvt_all(const float* __restrict__ W1, const float* __restrict__ W2,
             const float* __restrict__ W3, ushort* __restrict__ W1h,
             ushort* __restrict__ W2h, ushort* __restrict__ W3h) {
  const int n1 = HID * (576 / 8);
  const int n2 = HID * (HID / 8);
  int i = blockIdx.x * 256 + threadIdx.x;
  const float* src; ushort* dst; int Ks, Kd;
  if (i < n1)           { src = W1; dst = W1h; Ks = KIN; Kd = 576; }
  else if (i < n1 + n2) { src = W2; dst = W2h; Ks = HID; Kd = HID; i -= n1; }
  else if (i < n1 + 2 * n2) { src = W3; dst = W3h; Ks = HID; Kd = HID; i -= n1 + n2; }
  else return;
  int nblk = Kd >> 3;
  int row = i / nblk, k = (i - row * nblk) * 8;
  half8 v;
#pragma unroll
  for (int j = 0; j < 8; ++j) {
    int kk = k + j;
    float f = (kk < Ks) ? src[(size_t)row * Ks + kk] : 0.f;
    v[j] = (f16)f;
  }
  *(half8*)&dst[(size_t)row * Kd + k] = v;
}

// ---------------------------------------------------------------------------
// Per-round fp16 MFMA GEMM with COUNTED-VMCNT double-buffer (T4): next-kt
// loads stay in flight across the barrier (s_waitcnt vmcnt(8), never 0 in
// steady state) + raw s_barrier (no compiler vmcnt(0) drain). 128x128 tile,
// BK=64, 4 waves (2x2), 16x16x32 f16. Round semantics validated r8/r9.
// ---------------------------------------------------------------------------
template<int ACT, int L1, int SCAT>
__global__ __launch_bounds__(256)
void gemm_r(const ushort* __restrict__ A,
            const ushort* __restrict__ carry,
            const ushort* __restrict__ lsh,
            TL tl, int k0, int nk,
            const ushort* __restrict__ W, int ldw,
            const float* __restrict__ bias,
            ushort* __restrict__ C) {
  __shared__ ushort lds[32768];                   // 64KB: 2 x (X 16K | W 16K)
  char* ldsb = (char*)lds;
  const int tid = threadIdx.x;
  const int wv = tid >> 6, ln = tid & 63;
  const int bn0 = blockIdx.x * 128;
  const int br = blockIdx.y;
  const int t = tl.t[br >> 3];
  const size_t gr0 = (size_t)br * 128;
  const ushort* lbase = lsh + (size_t)t * BATCH * 64;

  f32x4 acc[4][4];
#pragma unroll
  for (int mi = 0; mi < 4; ++mi)
#pragma unroll
    for (int ni = 0; ni < 4; ++ni) acc[mi][ni] = (f32x4){0.f, 0.f, 0.f, 0.f};

  const int xr0 = (wv >> 1) * 64, nr0 = (wv & 1) * 64;
  const int l15 = ln & 15, l4 = ln >> 4;

#define STAGE(BI, KT)                                                         \
  do {                                                                        \
    _Pragma("unroll")                                                         \
    for (int i = 0; i < 4; ++i) {                                             \
      int qq = (i * 4 + wv) * 64 + ln;                                        \
      int r = qq >> 3, sl = qq & 7, ss = sl ^ (r & 7);                        \
      const ushort* src;                                                      \
      if (L1) {                                                               \
        int b_ = ((br & 7) << 7) + r;                                         \
        if ((KT) < 8) src = carry + (size_t)b_ * HID + (KT) * 64 + ss * 8;    \
        else          src = lbase + (size_t)b_ * 64 + ss * 8;                 \
      } else {                                                                \
        src = A + (gr0 + r) * (size_t)HID + (KT) * 64 + ss * 8;               \
      }                                                                       \
      __builtin_amdgcn_global_load_lds(                                       \
          (const __attribute__((address_space(1))) unsigned int*)src,         \
          (__attribute__((address_space(3))) unsigned int*)                   \
              (ldsb + (BI) * 32768 + (i * 4 + wv) * 1024), 16, 0, 0);         \
    }                                                                         \
    _Pragma("unroll")                                                         \
    for (int i = 0; i < 4; ++i) {                                             \
      int qq = (i * 4 + wv) * 64 + ln;                                        \
      int r = qq >> 3, sl = qq & 7, ss = sl ^ (r & 7);                        \
      const ushort* src = W + (size_t)(bn0 + r) * ldw + (KT) * 64 + ss * 8;   \
      __builtin_amdgcn_global_load_lds(                                       \
          (const __attribute__((address_space(1))) unsigned int*)src,         \
          (__attribute__((address_space(3))) unsigned int*)                   \
              (ldsb + (BI) * 32768 + 16384 + (i * 4 + wv) * 1024), 16, 0, 0); \
    }                                                                         \
  } while (0)

  STAGE(0, k0);
  int cur = 0;
  for (int kt = k0; kt < nk; ++kt) {
    const bool pf = (kt + 1 < nk);
    if (pf) {
      STAGE(cur ^ 1, kt + 1);                    // 8 more loads in flight
      asm volatile("s_waitcnt vmcnt(8)" ::: "memory");   // cur's 8 retired
    } else {
      asm volatile("s_waitcnt vmcnt(0)" ::: "memory");
    }
    __builtin_amdgcn_s_barrier();                // all waves: cur LDS ready
    __builtin_amdgcn_sched_barrier(0);           // rule 18: pin reads below
#pragma unroll
    for (int kk = 0; kk < 2; ++kk) {
      half8 xf[4], wf[4];
#pragma unroll
      for (int mi = 0; mi < 4; ++mi) {
        int r = xr0 + mi * 16 + l15;
        int ss = (kk * 4 + l4) ^ (r & 7);
        xf[mi] = *(const half8*)(ldsb + cur * 32768 + r * 128 + ss * 16);
      }
#pragma unroll
      for (int ni = 0; ni < 4; ++ni) {
        int r = nr0 + ni * 16 + l15;
        int ss = (kk * 4 + l4) ^ (r & 7);
        wf[ni] = *(const half8*)(ldsb + cur * 32768 + 16384 + r * 128 + ss * 16);
      }
#pragma unroll
      for (int mi = 0; mi < 4; ++mi)
#pragma unroll
        for (int ni = 0; ni < 4; ++ni)
          acc[mi][ni] = __builtin_amdgcn_mfma_f32_16x16x32_f16(wf[ni], xf[mi], acc[mi][ni], 0, 0, 0);
    }
    __builtin_amdgcn_sched_barrier(0);           // keep reads above barrier
    asm volatile("s_waitcnt lgkmcnt(0)" ::: "memory");   // LDS reads done
    __builtin_amdgcn_s_barrier();                // WAR: buffer may be reused
    cur ^= 1;
  }
#undef STAGE

  // ---- epilogue: bias + act + f16 pack, 8B stores ----
#pragma unroll
  for (int mi = 0; mi < 4; ++mi) {
    size_t gm;
    if (SCAT) gm = (size_t)t * BATCH + ((br & 7) << 7) + xr0 + mi * 16 + l15;
    else      gm = gr0 + xr0 + mi * 16 + l15;
#pragma unroll
    for (int ni = 0; ni < 4; ++ni) {
      int gn = bn0 + nr0 + ni * 16 + l4 * 4;
      f32x4 a = acc[mi][ni];
      union { f16 h[4]; ushort4 u; } cv;
#pragma unroll
      for (int j = 0; j < 4; ++j) {
        float v = a[j] + bias[gn + j];
        if (ACT == 1) v = fmaxf(v, 0.f);
        else { float xc = fminf(fmaxf(v, -9.f), 9.f); float e = __expf(2.f * xc); v = (e - 1.f) / (e + 1.f); }
        cv.h[j] = (f16)v;
      }
      *(ushort4*)&C[gm * HID + gn] = cv.u;
    }
  }
}

// ---------------------------------------------------------------------------
// out[b, t, :] = Hall[t][b][:] @ Wout^T. 4 lanes per row, shfl reduce.
// ---------------------------------------------------------------------------
__global__ __launch_bounds__(256)
void out_k(const ushort* __restrict__ Hall, const float* __restrict__ Wout,
           float* __restrict__ out) {
  const int tid = threadIdx.x;
  const int lane4 = tid & 3;
  const int row = blockIdx.x * 64 + (tid >> 2);   // t*1024 + b
  const int t = row >> 10, b = row & 1023;
  const ushort* hb = Hall + (size_t)row * HID;
  float a0 = 0.f, a1 = 0.f, a2 = 0.f;
#pragma unroll 4
  for (int q = 0; q < 16; ++q) {
    int k = (q * 4 + lane4) * 8;
    half8 hv8 = *(const half8*)&hb[k];
#pragma unroll
    for (int j = 0; j < 8; ++j) {
      float h = (float)hv8[j];
      a0 += h * Wout[k + j];
      a1 += h * Wout[512 + k + j];
      a2 += h * Wout[1024 + k + j];
    }
  }
  a0 += __shfl_xor(a0, 1); a0 += __shfl_xor(a0, 2);
  a1 += __shfl_xor(a1, 1); a1 += __shfl_xor(a1, 2);
  a2 += __shfl_xor(a2, 1); a2 += __shfl_xor(a2, 2);
  if (lane4 == 0) {
    float* o = out + ((size_t)b * WIN + t) * 3;
    o[0] = a0; o[1] = a1; o[2] = a2;
  }
}

// ---------------------------------------------------------------------------
extern "C" void kernel_launch(void* const* d_in, const int* in_sizes, int n_in,
                              void* d_out, int out_size, void* d_ws, size_t ws_size,
                              hipStream_t stream) {
  (void)n_in; (void)out_size; (void)ws_size; (void)in_sizes;
  const float* z    = (const float*)d_in[0];
  const float* W1   = (const float*)d_in[1];
  const float* b1   = (const float*)d_in[2];
  const float* W2   = (const float*)d_in[3];
  const float* b2   = (const float*)d_in[4];
  const float* W3   = (const float*)d_in[5];
  const float* b3   = (const float*)d_in[6];
  const float* Wout = (const float*)d_in[7];
  float* out = (float*)d_out;

  // ---- replicate _static_schedule exactly (numpy linspace doubles) ----
  double tb[1000], tt[64], tu[20];
  {
    double sb = 1.0 / 999.0; for (int i = 0; i < 1000; ++i) tb[i] = i * sb; tb[999] = 1.0;
    double st = 1.0 / 63.0;  for (int k = 0; k < 64; ++k)  tt[k] = k * st;  tt[63] = 1.0;
    for (int j = 0; j < 20; ++j) tu[j] = tb[50 * j];
  }
  auto ssr = [](const double* a, int n, double v) -> int {
    int lo = 0, hi = n;
    while (lo < hi) { int mid = (lo + hi) >> 1; if (a[mid] <= v) lo = mid + 1; else hi = mid; }
    return lo - 1;
  };
  Sched sc; int gates[64];
  {
    int u_indices[20];
    for (int j = 0; j < 20; ++j) u_indices[j] = ssr(tb, 1000, tu[j]);
    double u_times[80]; int nut = 0; int last = -1;
    for (int k = 1; k < 64; ++k) {
      int it = ssr(tb, 1000, tt[k]);
      int iu = ssr(tu, 20, tt[k]); if (iu < 0) iu = 0;
      if (iu != last) { u_times[nut++] = tu[iu]; last = iu; }
      sc.starts[k - 1] = u_indices[iu];
      sc.ends[k - 1] = it;
    }
    u_times[nut++] = tt[63];
    int qh = 0;
    for (int k = 0; k < 64; ++k) {
      if (qh < nut && tt[k] >= u_times[qh]) { ++qh; gates[k] = 1; } else gates[k] = 0;
    }
  }
  int seg[64], g[64], ng = 0, jlast = -1;
  for (int t = 0; t < WIN; ++t) {
    seg[t] = jlast;
    if (gates[t]) { g[ng] = t; jlast = ng; ++ng; }
  }

  // ---- workspace carve ----
  char* p = (char*)d_ws;
  ushort* lsh  = (ushort*)p; p += (size_t)WIN * BATCH * 64 * 2;        // 8.4 MB
  ushort* W1h  = (ushort*)p; p += (size_t)HID * 576 * 2;
  ushort* W2h  = (ushort*)p; p += (size_t)HID * HID * 2;
  ushort* W3h  = (ushort*)p; p += (size_t)HID * HID * 2;
  ushort* Hall = (ushort*)p; p += (size_t)WIN * BATCH * HID * 2;       // 67 MB
  ushort* act1 = (ushort*)p; p += (size_t)8 * BATCH * HID * 2;         // 8.4 MB
  ushort* act2 = (ushort*)p; p += (size_t)8 * BATCH * HID * 2;         // 8.4 MB

  float scale = (float)std::sqrt(1.0 / 999.0);
  logsig_scan<<<BATCH, 256, 0, stream>>>(z, sc, lsh, scale);
  cvt_all<<<(HID * 72 + 2 * HID * 64 + 255) / 256, 256, 0, stream>>>(
      W1, W2, W3, W1h, W2h, W3h);

  // ---- serial per-segment rounds: 3 pipelined GEMM launches each ----
  for (int r = 0; r < ng; ++r) {
    TL tlr; int cnt = 0;
    for (int t = 0; t < WIN && cnt < 8; ++t)
      if (seg[t] == r - 1) tlr.t[cnt++] = t;
    if (cnt == 0) continue;
    for (int i = cnt; i < 8; ++i) tlr.t[i] = tlr.t[0];
    const ushort* carry = (r == 0) ? nullptr : Hall + (size_t)g[r - 1] * (BATCH * HID);
    int k0 = (r == 0) ? 8 : 0;                    // round 0: zero carry, ls only
    dim3 gg(4, cnt * 8), gb(256);
    gemm_r<1, 1, 0><<<gg, gb, 0, stream>>>(nullptr, carry, lsh, tlr, k0, 9,
                                           W1h, 576, b1, act1);
    gemm_r<1, 0, 0><<<gg, gb, 0, stream>>>(act1, nullptr, lsh, tlr, 0, 8,
                                           W2h, HID, b2, act2);
    gemm_r<2, 0, 1><<<gg, gb, 0, stream>>>(act2, nullptr, lsh, tlr, 0, 8,
                                           W3h, HID, b3, Hall);
  }

  out_k<<<WIN * BATCH / 64, 256, 0, stream>>>(Hall, Wout, out);
}